// Round 1
// baseline (241.926 us; speedup 1.0000x reference)
//
#include <hip/hip_runtime.h>

// MultiheadAttention: B=2, S=2048, D=1024, H=16, DH=64, NF=4
// Pipeline:
//   1. cvt x, Wq, Wk, Wv -> bf16 (ws)
//   2. Weff = sum_f w[f]*Wout[f] -> bf16 ; beff = w @ bout -> f32
//   3. q/k/v = x @ W^T + b   (bf16 MFMA GEMM, 128x128 tile, global_load_lds)
//   4. vt = per-head transpose of v  ([B,H,DH,S])
//   5. flash attention (causal), bf16 MFMA, online softmax
//   6. out = attn @ Weff^T + beff  (f32 output)

typedef unsigned short u16;
typedef __bf16 bf16_t;
typedef bf16_t bf16x8 __attribute__((ext_vector_type(8)));
typedef float f32x4 __attribute__((ext_vector_type(4)));
typedef u16 u16x8 __attribute__((ext_vector_type(8)));
typedef u16 u16x4 __attribute__((ext_vector_type(4)));

#define DEV __device__ __forceinline__

DEV u16 f2bf(float f) {  // round-to-nearest-even f32 -> bf16
  unsigned u = __float_as_uint(f);
  u += 0x7FFFu + ((u >> 16) & 1u);
  return (u16)(u >> 16);
}

DEV void async_ld16(const void* g, void* lds_wave_uniform) {
  // dst is wave-uniform base; HW writes base + lane*16
  __builtin_amdgcn_global_load_lds(
      (const __attribute__((address_space(1))) void*)g,
      (__attribute__((address_space(3))) void*)lds_wave_uniform, 16, 0, 0);
}

// ---------------- f32 -> bf16 conversion ----------------
__global__ __launch_bounds__(256) void cvt_bf16_kernel(
    const float* __restrict__ in, u16* __restrict__ out, int n4) {
  int i = blockIdx.x * blockDim.x + threadIdx.x;
  const int stride = gridDim.x * blockDim.x;
  for (; i < n4; i += stride) {
    const float4 v = ((const float4*)in)[i];
    u16x4 o;
    o[0] = f2bf(v.x); o[1] = f2bf(v.y); o[2] = f2bf(v.z); o[3] = f2bf(v.w);
    ((u16x4*)out)[i] = o;
  }
}

// ---------------- Weff = sum_f w[f]*Wout[f]; beff = w @ bout ----------------
__global__ __launch_bounds__(256) void build_weff_kernel(
    const float* __restrict__ w4, const float* __restrict__ Wout,
    const float* __restrict__ bout, u16* __restrict__ Weff,
    float* __restrict__ beff) {
  constexpr int DD4 = 262144;  // (1024*1024)/4
  const int i = blockIdx.x * blockDim.x + threadIdx.x;
  if (i >= DD4) return;
  const float w0 = w4[0], w1 = w4[1], w2 = w4[2], w3 = w4[3];
  const float4* W = (const float4*)Wout;
  const float4 a = W[i], b1 = W[DD4 + i], b2 = W[2 * DD4 + i], b3 = W[3 * DD4 + i];
  u16x4 o;
  o[0] = f2bf(w0 * a.x + w1 * b1.x + w2 * b2.x + w3 * b3.x);
  o[1] = f2bf(w0 * a.y + w1 * b1.y + w2 * b2.y + w3 * b3.y);
  o[2] = f2bf(w0 * a.z + w1 * b1.z + w2 * b2.z + w3 * b3.z);
  o[3] = f2bf(w0 * a.w + w1 * b1.w + w2 * b2.w + w3 * b3.w);
  ((u16x4*)Weff)[i] = o;
  if (i < 256) {  // beff: 1024 floats = 256 float4
    const float4* B4 = (const float4*)bout;
    const float4 ba = B4[i], c1 = B4[256 + i], c2 = B4[512 + i], c3 = B4[768 + i];
    float4 ob;
    ob.x = w0 * ba.x + w1 * c1.x + w2 * c2.x + w3 * c3.x;
    ob.y = w0 * ba.y + w1 * c1.y + w2 * c2.y + w3 * c3.y;
    ob.z = w0 * ba.z + w1 * c1.z + w2 * c2.z + w3 * c3.z;
    ob.w = w0 * ba.w + w1 * c1.w + w2 * c2.w + w3 * c3.w;
    ((float4*)beff)[i] = ob;
  }
}

// ---------------- GEMM: C[M,N] = A[M,K](bf16) @ Bw[N,K]^T(bf16) + bias ----------------
// 128x128 tile, BK=32, 4 waves (2x2), each wave 64x64 = 4x4 frags of 16x16.
template <typename OutT>
__global__ __launch_bounds__(256) void gemm_bt_kernel(
    const u16* __restrict__ A, const u16* __restrict__ Bw,
    const float* __restrict__ bias, OutT* __restrict__ C, int M, int N, int K) {
  constexpr int BM = 128, BK = 32;
  __shared__ u16 As[BM * BK];  // [m][k], 64B rows
  __shared__ u16 Bs[BM * BK];  // [n][k]
  const int tid = threadIdx.x;
  const int w = tid >> 6, lane = tid & 63;
  const int l15 = lane & 15, l4 = lane >> 4;
  const int wr = w >> 1, wc = w & 1;
  const long m0 = (long)blockIdx.y * BM, n0 = (long)blockIdx.x * BM;

  f32x4 acc[4][4] = {};

  for (int kt = 0; kt < K; kt += BK) {
    if (kt) __syncthreads();
#pragma unroll
    for (int is = 0; is < 2; ++is) {
      const int boff = tid * 16 + is * 4096;  // byte offset within 8KB tile
      const int r = boff >> 6;                // row (64B per row)
      const int c = (boff & 63) >> 1;         // col element
      async_ld16(A + (m0 + r) * K + kt + c, &As[w * 512 + is * 2048]);
      async_ld16(Bw + (n0 + r) * K + kt + c, &Bs[w * 512 + is * 2048]);
    }
    __syncthreads();  // compiler drains vmcnt before barrier
    bf16x8 af[4], bfrag[4];
#pragma unroll
    for (int i = 0; i < 4; ++i) {
      af[i] = *(const bf16x8*)&As[(wr * 64 + i * 16 + l15) * BK + l4 * 8];
      bfrag[i] = *(const bf16x8*)&Bs[(wc * 64 + i * 16 + l15) * BK + l4 * 8];
    }
#pragma unroll
    for (int i = 0; i < 4; ++i)
#pragma unroll
      for (int j = 0; j < 4; ++j)
        acc[i][j] = __builtin_amdgcn_mfma_f32_16x16x32_bf16(af[i], bfrag[j],
                                                            acc[i][j], 0, 0, 0);
  }

#pragma unroll
  for (int i = 0; i < 4; ++i) {
    const long row0 = m0 + wr * 64 + i * 16 + l4 * 4;
#pragma unroll
    for (int j = 0; j < 4; ++j) {
      const long col = n0 + wc * 64 + j * 16 + l15;
      const float bb = bias[col];
#pragma unroll
      for (int r = 0; r < 4; ++r) {
        const float v = acc[i][j][r] + bb;
        if constexpr (sizeof(OutT) == 2)
          C[(row0 + r) * N + col] = (OutT)f2bf(v);
        else
          C[(row0 + r) * N + col] = (OutT)v;
      }
    }
  }
}

// ---------------- per-head V transpose: Vt[b,h,d,s] = V[b*s, h*64+d] ----------------
__global__ __launch_bounds__(256) void transpose_v_kernel(
    const u16* __restrict__ V, u16* __restrict__ Vt) {
  constexpr int S = 2048, D = 1024, DH = 64;
  __shared__ u16 T[64 * 72];
  const int tid = threadIdx.x;
  const int bh = blockIdx.y, b = bh >> 4, h = bh & 15;
  const int s0 = blockIdx.x * 64;
#pragma unroll
  for (int is = 0; is < 2; ++is) {
    const int sl = tid + is * 256;
    const int r = sl >> 3, c0 = (sl & 7) * 8;
    *(u16x8*)&T[r * 72 + c0] =
        *(const u16x8*)(V + (size_t)(b * S + s0 + r) * D + h * DH + c0);
  }
  __syncthreads();
#pragma unroll
  for (int is = 0; is < 2; ++is) {
    const int sl = tid + is * 256;
    const int d = sl >> 3, k0 = (sl & 7) * 8;
    u16x8 o;
#pragma unroll
    for (int j = 0; j < 8; ++j) o[j] = T[(k0 + j) * 72 + d];
    *(u16x8*)(Vt + (size_t)(bh * DH + d) * S + s0 + k0) = o;
  }
}

// ---------------- causal flash attention ----------------
// grid (S/64, B*H). 4 waves x 16 q-rows. KVBLK=64.
// Ks: [key][feat] padded 72; Vs: [d][key] padded 72 (from pre-transposed Vt);
// Ps per wave: [q16][key64] padded 72 (C-layout -> A-layout round trip).
__global__ __launch_bounds__(256) void flash_kernel(
    const u16* __restrict__ Q, const u16* __restrict__ Kg,
    const u16* __restrict__ Vt, u16* __restrict__ O) {
  constexpr int S = 2048, D = 1024, DH = 64;
  __shared__ u16 Ks[64 * 72];
  __shared__ u16 Vs[64 * 72];
  __shared__ u16 Ps[4][16 * 72];
  const int tid = threadIdx.x;
  const int w = tid >> 6, lane = tid & 63;
  const int l15 = lane & 15, l4 = lane >> 4;
  const int bh = blockIdx.y, b = bh >> 4, h = bh & 15;
  const int q0 = blockIdx.x * 64;
  const int qw = q0 + w * 16;

  // Q fragments held in registers for the whole block row
  bf16x8 qf[2];
  {
    const u16* qp = Q + (size_t)(b * S + qw + l15) * D + h * DH + l4 * 8;
    qf[0] = *(const bf16x8*)qp;
    qf[1] = *(const bf16x8*)(qp + 32);
  }

  f32x4 acc_o[4] = {};
  float m_run[4] = {-1e30f, -1e30f, -1e30f, -1e30f};
  float l_run[4] = {0.f, 0.f, 0.f, 0.f};

  for (int kv0 = 0; kv0 <= q0; kv0 += 64) {
    const bool diag = (kv0 == q0);
    // ---- stage K tile [key][feat] and V tile [d][key] ----
#pragma unroll
    for (int is = 0; is < 2; ++is) {
      const int sl = tid + is * 256;
      const int rr = sl >> 3, c0 = (sl & 7) * 8;
      *(u16x8*)&Ks[rr * 72 + c0] =
          *(const u16x8*)(Kg + (size_t)(b * S + kv0 + rr) * D + h * DH + c0);
      *(u16x8*)&Vs[rr * 72 + c0] =
          *(const u16x8*)(Vt + (size_t)(bh * DH + rr) * S + kv0 + c0);
    }
    __syncthreads();
    // ---- S = Q K^T ----
    f32x4 accs[4] = {};
#pragma unroll
    for (int cb = 0; cb < 4; ++cb) {
      const bf16x8 kf0 = *(const bf16x8*)&Ks[(cb * 16 + l15) * 72 + l4 * 8];
      const bf16x8 kf1 = *(const bf16x8*)&Ks[(cb * 16 + l15) * 72 + 32 + l4 * 8];
      accs[cb] = __builtin_amdgcn_mfma_f32_16x16x32_bf16(qf[0], kf0, accs[cb], 0, 0, 0);
      accs[cb] = __builtin_amdgcn_mfma_f32_16x16x32_bf16(qf[1], kf1, accs[cb], 0, 0, 0);
    }
    // ---- scale + causal mask ----
    float sc[4][4];
#pragma unroll
    for (int cb = 0; cb < 4; ++cb)
#pragma unroll
      for (int r = 0; r < 4; ++r) {
        float s_ = accs[cb][r] * 0.125f;  // 1/sqrt(64)
        if (diag) {
          const int key = kv0 + cb * 16 + l15;
          const int qr = qw + l4 * 4 + r;
          if (key > qr) s_ = -1e30f;
        }
        sc[cb][r] = s_;
      }
    // ---- online softmax: row max over 64 keys (4 local + shfl over 16 lanes) ----
    float mx[4];
#pragma unroll
    for (int r = 0; r < 4; ++r)
      mx[r] = fmaxf(fmaxf(sc[0][r], sc[1][r]), fmaxf(sc[2][r], sc[3][r]));
#pragma unroll
    for (int off = 1; off <= 8; off <<= 1)
#pragma unroll
      for (int r = 0; r < 4; ++r) mx[r] = fmaxf(mx[r], __shfl_xor(mx[r], off));
    float corr[4];
#pragma unroll
    for (int r = 0; r < 4; ++r) {
      const float mn = fmaxf(m_run[r], mx[r]);
      corr[r] = __expf(m_run[r] - mn);
      m_run[r] = mn;
    }
    float p[4][4];
    float rs[4] = {0.f, 0.f, 0.f, 0.f};
#pragma unroll
    for (int cb = 0; cb < 4; ++cb)
#pragma unroll
      for (int r = 0; r < 4; ++r) {
        p[cb][r] = __expf(sc[cb][r] - m_run[r]);
        rs[r] += p[cb][r];
      }
#pragma unroll
    for (int off = 1; off <= 8; off <<= 1)
#pragma unroll
      for (int r = 0; r < 4; ++r) rs[r] += __shfl_xor(rs[r], off);
#pragma unroll
    for (int r = 0; r < 4; ++r) l_run[r] = l_run[r] * corr[r] + rs[r];
#pragma unroll
    for (int db = 0; db < 4; ++db)
#pragma unroll
      for (int r = 0; r < 4; ++r) acc_o[db][r] *= corr[r];
    // ---- P: C-layout -> per-wave LDS -> A-layout ----
#pragma unroll
    for (int cb = 0; cb < 4; ++cb)
#pragma unroll
      for (int r = 0; r < 4; ++r)
        Ps[w][(l4 * 4 + r) * 72 + cb * 16 + l15] = f2bf(p[cb][r]);
    __syncthreads();
    const bf16x8 pa0 = *(const bf16x8*)&Ps[w][l15 * 72 + l4 * 8];
    const bf16x8 pa1 = *(const bf16x8*)&Ps[w][l15 * 72 + 32 + l4 * 8];
    // ---- O += P V ----
#pragma unroll
    for (int db = 0; db < 4; ++db) {
      const bf16x8 vf0 = *(const bf16x8*)&Vs[(db * 16 + l15) * 72 + l4 * 8];
      const bf16x8 vf1 = *(const bf16x8*)&Vs[(db * 16 + l15) * 72 + 32 + l4 * 8];
      acc_o[db] = __builtin_amdgcn_mfma_f32_16x16x32_bf16(pa0, vf0, acc_o[db], 0, 0, 0);
      acc_o[db] = __builtin_amdgcn_mfma_f32_16x16x32_bf16(pa1, vf1, acc_o[db], 0, 0, 0);
    }
    __syncthreads();  // PV reads done before next stage overwrites Ks/Vs
  }
  // ---- epilogue: O / l ----
#pragma unroll
  for (int db = 0; db < 4; ++db) {
    const int col = h * DH + db * 16 + l15;
#pragma unroll
    for (int r = 0; r < 4; ++r) {
      const int row = b * S + qw + l4 * 4 + r;
      O[(size_t)row * D + col] = f2bf(acc_o[db][r] / l_run[r]);
    }
  }
}

// ---------------- launch ----------------
extern "C" void kernel_launch(void* const* d_in, const int* in_sizes, int n_in,
                              void* d_out, int out_size, void* d_ws, size_t ws_size,
                              hipStream_t stream) {
  (void)in_sizes; (void)n_in; (void)out_size;
  const float* x   = (const float*)d_in[0];
  const float* wts = (const float*)d_in[1];
  const float* Wq  = (const float*)d_in[2];
  const float* bq  = (const float*)d_in[3];
  const float* Wk  = (const float*)d_in[4];
  const float* bk  = (const float*)d_in[5];
  const float* Wv  = (const float*)d_in[6];
  const float* bv  = (const float*)d_in[7];
  const float* Wo  = (const float*)d_in[8];
  const float* bo  = (const float*)d_in[9];
  float* out = (float*)d_out;

  if (ws_size < 58724352) return;  // need ~56 MB scratch

  char* ws = (char*)d_ws;
  u16* xbf  = (u16*)(ws + 0);          // [4096,1024] bf16
  u16* qbf  = (u16*)(ws + 8388608);
  u16* kbf  = (u16*)(ws + 16777216);
  u16* vbf  = (u16*)(ws + 25165824);
  u16* vt   = (u16*)(ws + 33554432);   // [B,H,DH,S] bf16
  u16* attn = (u16*)(ws + 41943040);   // [4096,1024] bf16
  u16* wqb  = (u16*)(ws + 50331648);   // [1024,1024] bf16
  u16* wkb  = (u16*)(ws + 52428800);
  u16* wvb  = (u16*)(ws + 54525952);
  u16* wob  = (u16*)(ws + 56623104);   // Weff bf16
  float* beff = (float*)(ws + 58720256);

  cvt_bf16_kernel<<<2048, 256, 0, stream>>>(x, xbf, 1048576);
  cvt_bf16_kernel<<<1024, 256, 0, stream>>>(Wq, wqb, 262144);
  cvt_bf16_kernel<<<1024, 256, 0, stream>>>(Wk, wkb, 262144);
  cvt_bf16_kernel<<<1024, 256, 0, stream>>>(Wv, wvb, 262144);
  build_weff_kernel<<<1024, 256, 0, stream>>>(wts, Wo, bo, wob, beff);

  const dim3 gg(8, 32);  // N/128, M/128
  gemm_bt_kernel<u16><<<gg, 256, 0, stream>>>(xbf, wqb, bq, qbf, 4096, 1024, 1024);
  gemm_bt_kernel<u16><<<gg, 256, 0, stream>>>(xbf, wkb, bk, kbf, 4096, 1024, 1024);
  gemm_bt_kernel<u16><<<gg, 256, 0, stream>>>(xbf, wvb, bv, vbf, 4096, 1024, 1024);
  transpose_v_kernel<<<dim3(32, 32), 256, 0, stream>>>(vbf, vt);
  flash_kernel<<<dim3(32, 32), 256, 0, stream>>>(qbf, kbf, vt, attn);
  gemm_bt_kernel<float><<<gg, 256, 0, stream>>>(attn, wob, beff, out, 4096, 1024, 1024);
}

// Round 2
// 152.900 us; speedup vs baseline: 1.5823x; 1.5823x over previous
//
#include <hip/hip_runtime.h>

// MultiheadAttention: B=2, S=2048, D=1024, H=16, DH=64, NF=4
// Pipeline:
//   1. cvt x -> bf16; cvt Wq|Wk|Wv -> one contiguous [3072,1024] bf16
//   2. Weff = sum_f w[f]*Wout[f] -> bf16 ; beff = w @ bout -> f32
//   3. qkv = x @ Wqkv^T + b (one fused MFMA GEMM; q pre-scaled by log2e/sqrt(DH))
//   4. vt = per-head transpose of v  ([B,H,DH,S])
//   5. flash attention (causal), paired q-tiles for perfect balance,
//      double-buffered K/V via global_load_lds + XOR swizzle, 1 barrier/step
//   6. out = attn @ Weff^T + beff  (f32 output)

typedef unsigned short u16;
typedef __bf16 bf16_t;
typedef bf16_t bf16x8 __attribute__((ext_vector_type(8)));
typedef float f32x4 __attribute__((ext_vector_type(4)));
typedef u16 u16x8 __attribute__((ext_vector_type(8)));
typedef u16 u16x4 __attribute__((ext_vector_type(4)));

#define DEV __device__ __forceinline__

DEV u16 f2bf(float f) {  // round-to-nearest-even f32 -> bf16
  unsigned u = __float_as_uint(f);
  u += 0x7FFFu + ((u >> 16) & 1u);
  return (u16)(u >> 16);
}

DEV void async_ld16(const void* g, void* lds_wave_uniform) {
  // dst is wave-uniform base; HW writes base + lane*16. Global src is per-lane.
  __builtin_amdgcn_global_load_lds(
      (const __attribute__((address_space(1))) void*)g,
      (__attribute__((address_space(3))) void*)lds_wave_uniform, 16, 0, 0);
}

// ---------------- f32 -> bf16 conversion ----------------
__global__ __launch_bounds__(256) void cvt_bf16_kernel(
    const float* __restrict__ in, u16* __restrict__ out, int n4) {
  int i = blockIdx.x * blockDim.x + threadIdx.x;
  const int stride = gridDim.x * blockDim.x;
  for (; i < n4; i += stride) {
    const float4 v = ((const float4*)in)[i];
    u16x4 o;
    o[0] = f2bf(v.x); o[1] = f2bf(v.y); o[2] = f2bf(v.z); o[3] = f2bf(v.w);
    ((u16x4*)out)[i] = o;
  }
}

// ---------------- Weff = sum_f w[f]*Wout[f]; beff = w @ bout ----------------
__global__ __launch_bounds__(256) void build_weff_kernel(
    const float* __restrict__ w4, const float* __restrict__ Wout,
    const float* __restrict__ bout, u16* __restrict__ Weff,
    float* __restrict__ beff) {
  constexpr int DD4 = 262144;  // (1024*1024)/4
  const int i = blockIdx.x * blockDim.x + threadIdx.x;
  if (i >= DD4) return;
  const float w0 = w4[0], w1 = w4[1], w2 = w4[2], w3 = w4[3];
  const float4* W = (const float4*)Wout;
  const float4 a = W[i], b1 = W[DD4 + i], b2 = W[2 * DD4 + i], b3 = W[3 * DD4 + i];
  u16x4 o;
  o[0] = f2bf(w0 * a.x + w1 * b1.x + w2 * b2.x + w3 * b3.x);
  o[1] = f2bf(w0 * a.y + w1 * b1.y + w2 * b2.y + w3 * b3.y);
  o[2] = f2bf(w0 * a.z + w1 * b1.z + w2 * b2.z + w3 * b3.z);
  o[3] = f2bf(w0 * a.w + w1 * b1.w + w2 * b2.w + w3 * b3.w);
  ((u16x4*)Weff)[i] = o;
  if (i < 256) {  // beff: 1024 floats = 256 float4
    const float4* B4 = (const float4*)bout;
    const float4 ba = B4[i], c1 = B4[256 + i], c2 = B4[512 + i], c3 = B4[768 + i];
    float4 ob;
    ob.x = w0 * ba.x + w1 * c1.x + w2 * c2.x + w3 * c3.x;
    ob.y = w0 * ba.y + w1 * c1.y + w2 * c2.y + w3 * c3.y;
    ob.z = w0 * ba.z + w1 * c1.z + w2 * c2.z + w3 * c3.z;
    ob.w = w0 * ba.w + w1 * c1.w + w2 * c2.w + w3 * c3.w;
    ((float4*)beff)[i] = ob;
  }
}

// ---------------- generic GEMM: C[M,N] = A[M,K] @ Bw[N,K]^T + bias ----------------
// 128x128 tile, BK=32, 4 waves (2x2), each wave 64x64 = 4x4 frags of 16x16.
template <typename OutT>
__global__ __launch_bounds__(256) void gemm_bt_kernel(
    const u16* __restrict__ A, const u16* __restrict__ Bw,
    const float* __restrict__ bias, OutT* __restrict__ C, int M, int N, int K) {
  constexpr int BM = 128, BK = 32;
  __shared__ u16 As[BM * BK];  // [m][k], 64B rows
  __shared__ u16 Bs[BM * BK];  // [n][k]
  const int tid = threadIdx.x;
  const int w = tid >> 6, lane = tid & 63;
  const int l15 = lane & 15, l4 = lane >> 4;
  const int wr = w >> 1, wc = w & 1;
  const long m0 = (long)blockIdx.y * BM, n0 = (long)blockIdx.x * BM;

  f32x4 acc[4][4] = {};

  for (int kt = 0; kt < K; kt += BK) {
    if (kt) __syncthreads();
#pragma unroll
    for (int is = 0; is < 2; ++is) {
      const int boff = tid * 16 + is * 4096;  // byte offset within 8KB tile
      const int r = boff >> 6;                // row (64B per row)
      const int c = (boff & 63) >> 1;         // col element
      async_ld16(A + (m0 + r) * K + kt + c, &As[w * 512 + is * 2048]);
      async_ld16(Bw + (n0 + r) * K + kt + c, &Bs[w * 512 + is * 2048]);
    }
    __syncthreads();
    bf16x8 af[4], bfrag[4];
#pragma unroll
    for (int i = 0; i < 4; ++i) {
      af[i] = *(const bf16x8*)&As[(wr * 64 + i * 16 + l15) * BK + l4 * 8];
      bfrag[i] = *(const bf16x8*)&Bs[(wc * 64 + i * 16 + l15) * BK + l4 * 8];
    }
#pragma unroll
    for (int i = 0; i < 4; ++i)
#pragma unroll
      for (int j = 0; j < 4; ++j)
        acc[i][j] = __builtin_amdgcn_mfma_f32_16x16x32_bf16(af[i], bfrag[j],
                                                            acc[i][j], 0, 0, 0);
  }

#pragma unroll
  for (int i = 0; i < 4; ++i) {
    const long row0 = m0 + wr * 64 + i * 16 + l4 * 4;
#pragma unroll
    for (int j = 0; j < 4; ++j) {
      const long col = n0 + wc * 64 + j * 16 + l15;
      const float bb = bias[col];
#pragma unroll
      for (int r = 0; r < 4; ++r) {
        const float v = acc[i][j][r] + bb;
        if constexpr (sizeof(OutT) == 2)
          C[(row0 + r) * N + col] = (OutT)f2bf(v);
        else
          C[(row0 + r) * N + col] = (OutT)v;
      }
    }
  }
}

// ---------------- fused QKV GEMM: [4096,1024] x [3072,1024]^T ----------------
// grid (24, 32): blockIdx.x selects segment (q/k/v) and column block.
// Q output pre-scaled by log2e / sqrt(DH) so flash softmax can use exp2.
__global__ __launch_bounds__(256) void gemm_qkv_kernel(
    const u16* __restrict__ A, const u16* __restrict__ Bw,
    const float* __restrict__ bq, const float* __restrict__ bk,
    const float* __restrict__ bv, u16* __restrict__ qo, u16* __restrict__ ko,
    u16* __restrict__ vo) {
  constexpr int K = 1024, BK = 32;
  __shared__ u16 As[128 * BK];
  __shared__ u16 Bs[128 * BK];
  const int tid = threadIdx.x;
  const int w = tid >> 6, lane = tid & 63;
  const int l15 = lane & 15, l4 = lane >> 4;
  const int wr = w >> 1, wc = w & 1;
  const long m0 = (long)blockIdx.y * 128, n0 = (long)blockIdx.x * 128;
  const int seg = blockIdx.x >> 3;  // 0=q 1=k 2=v
  const float* bias = seg == 0 ? bq : (seg == 1 ? bk : bv);
  u16* outp = seg == 0 ? qo : (seg == 1 ? ko : vo);
  const float scale = seg == 0 ? 0.18033688011112042f : 1.0f;  // log2e/8

  f32x4 acc[4][4] = {};

  for (int kt = 0; kt < K; kt += BK) {
    if (kt) __syncthreads();
#pragma unroll
    for (int is = 0; is < 2; ++is) {
      const int boff = tid * 16 + is * 4096;
      const int r = boff >> 6;
      const int c = (boff & 63) >> 1;
      async_ld16(A + (m0 + r) * K + kt + c, &As[w * 512 + is * 2048]);
      async_ld16(Bw + (n0 + r) * K + kt + c, &Bs[w * 512 + is * 2048]);
    }
    __syncthreads();
    bf16x8 af[4], bfrag[4];
#pragma unroll
    for (int i = 0; i < 4; ++i) {
      af[i] = *(const bf16x8*)&As[(wr * 64 + i * 16 + l15) * BK + l4 * 8];
      bfrag[i] = *(const bf16x8*)&Bs[(wc * 64 + i * 16 + l15) * BK + l4 * 8];
    }
#pragma unroll
    for (int i = 0; i < 4; ++i)
#pragma unroll
      for (int j = 0; j < 4; ++j)
        acc[i][j] = __builtin_amdgcn_mfma_f32_16x16x32_bf16(af[i], bfrag[j],
                                                            acc[i][j], 0, 0, 0);
  }

#pragma unroll
  for (int i = 0; i < 4; ++i) {
    const long row0 = m0 + wr * 64 + i * 16 + l4 * 4;
#pragma unroll
    for (int j = 0; j < 4; ++j) {
      const long col = n0 + wc * 64 + j * 16 + l15 - (long)seg * 1024;
      const float bb = bias[col];
#pragma unroll
      for (int r = 0; r < 4; ++r)
        outp[(row0 + r) * 1024 + col] = f2bf((acc[i][j][r] + bb) * scale);
    }
  }
}

// ---------------- per-head V transpose: Vt[b,h,d,s] = V[b*s, h*64+d] ----------------
__global__ __launch_bounds__(256) void transpose_v_kernel(
    const u16* __restrict__ V, u16* __restrict__ Vt) {
  constexpr int S = 2048, D = 1024, DH = 64;
  __shared__ u16 T[64 * 72];
  const int tid = threadIdx.x;
  const int bh = blockIdx.y, b = bh >> 4, h = bh & 15;
  const int s0 = blockIdx.x * 64;
#pragma unroll
  for (int is = 0; is < 2; ++is) {
    const int sl = tid + is * 256;
    const int r = sl >> 3, c0 = (sl & 7) * 8;
    *(u16x8*)&T[r * 72 + c0] =
        *(const u16x8*)(V + (size_t)(b * S + s0 + r) * D + h * DH + c0);
  }
  __syncthreads();
#pragma unroll
  for (int is = 0; is < 2; ++is) {
    const int sl = tid + is * 256;
    const int d = sl >> 3, k0 = (sl & 7) * 8;
    u16x8 o;
#pragma unroll
    for (int j = 0; j < 8; ++j) o[j] = T[(k0 + j) * 72 + d];
    *(u16x8*)(Vt + (size_t)(bh * DH + d) * S + s0 + k0) = o;
  }
}

// ---------------- causal flash attention v2 ----------------
// grid (16, 32). Workgroup p handles q-tiles (p, 31-p) sequentially -> every
// workgroup does exactly 33 KV steps (perfect balance, 2 blocks/CU).
// K/V double-buffered in LDS via global_load_lds (linear dest, inverse-swizzled
// global source, swizzled ds_read). One __syncthreads per step.
// P round-trip is wave-local LDS: only s_waitcnt lgkmcnt(0), no barrier.
__global__ __launch_bounds__(256) void flash_kernel(
    const u16* __restrict__ Q, const u16* __restrict__ Kg,
    const u16* __restrict__ Vt, u16* __restrict__ O) {
  constexpr int S = 2048, D = 1024, DH = 64, NQT = 32;
  __shared__ u16 Ks[2][64 * 64];  // [key][feat], XOR-swizzled chunks
  __shared__ u16 Vs[2][64 * 64];  // [d][key], XOR-swizzled chunks
  __shared__ u16 Ps[4][16 * 72];  // per-wave P round-trip
  const int tid = threadIdx.x;
  const int w = tid >> 6, lane = tid & 63;
  const int l15 = lane & 15, l4 = lane >> 4;
  const int bh = blockIdx.y, b = bh >> 4, h = bh & 15;
  const int pair = blockIdx.x;

  const u16* Kbh = Kg + (size_t)b * S * D + h * DH;
  const u16* Vbh = Vt + (size_t)bh * DH * S;

  // per-lane staging source offsets (computed once)
  // chunk within 8KB tile = (w*2+is)*64 + lane; row = chunk>>3; lds slot = chunk&7
  // source col chunk = slot ^ (row & 7)   (XOR involution)
  int src_off[2];  // element offset within a K row / V row for this lane
  int row_of[2];
#pragma unroll
  for (int is = 0; is < 2; ++is) {
    const int chunk = (w * 2 + is) * 64 + lane;
    row_of[is] = chunk >> 3;
    src_off[is] = ((chunk & 7) ^ (row_of[is] & 7)) * 8;
  }

  for (int half = 0; half < 2; ++half) {
    const int qt = half == 0 ? pair : (NQT - 1 - pair);
    const int q0 = qt * 64;
    const int qw = q0 + w * 16;
    const int nsteps = qt + 1;

    // Q fragments (already scaled by log2e/sqrt(DH) in the QKV GEMM)
    bf16x8 qf[2];
    {
      const u16* qp = Q + (size_t)(b * S + qw + l15) * D + h * DH + l4 * 8;
      qf[0] = *(const bf16x8*)qp;
      qf[1] = *(const bf16x8*)(qp + 32);
    }

    f32x4 acc_o[4] = {};
    float m_run[4] = {-1e30f, -1e30f, -1e30f, -1e30f};
    float l_run[4] = {0.f, 0.f, 0.f, 0.f};

    // prologue: stage tile 0 into buf 0
#pragma unroll
    for (int is = 0; is < 2; ++is) {
      async_ld16(Kbh + (size_t)row_of[is] * D + src_off[is],
                 &Ks[0][(w * 2 + is) * 512]);
      async_ld16(Vbh + (size_t)row_of[is] * S + src_off[is],
                 &Vs[0][(w * 2 + is) * 512]);
    }
    __syncthreads();  // drains vmcnt before s_barrier

    for (int it = 0; it < nsteps; ++it) {
      const int buf = it & 1;
      const u16* KsB = Ks[buf];
      const u16* VsB = Vs[buf];
      // async prefetch of next tile into buf^1 (hides under compute)
      if (it + 1 < nsteps) {
        const int kv1 = (it + 1) * 64;
#pragma unroll
        for (int is = 0; is < 2; ++is) {
          async_ld16(Kbh + (size_t)(kv1 + row_of[is]) * D + src_off[is],
                     &Ks[buf ^ 1][(w * 2 + is) * 512]);
          async_ld16(Vbh + (size_t)row_of[is] * S + kv1 + src_off[is],
                     &Vs[buf ^ 1][(w * 2 + is) * 512]);
        }
      }
      // ---- S = Q K^T (swizzled ds_read) ----
      f32x4 accs[4] = {};
      const int sw = l15 & 7;
#pragma unroll
      for (int cb = 0; cb < 4; ++cb) {
        const int row = cb * 16 + l15;
        const bf16x8 kf0 = *(const bf16x8*)&KsB[row * 64 + ((l4 ^ sw) * 8)];
        const bf16x8 kf1 = *(const bf16x8*)&KsB[row * 64 + (((l4 + 4) ^ sw) * 8)];
        accs[cb] = __builtin_amdgcn_mfma_f32_16x16x32_bf16(qf[0], kf0, accs[cb], 0, 0, 0);
        accs[cb] = __builtin_amdgcn_mfma_f32_16x16x32_bf16(qf[1], kf1, accs[cb], 0, 0, 0);
      }
      // ---- causal mask on diagonal tile (wave-uniform branch) ----
      float sc[4][4];
      const bool diag = (it == nsteps - 1) && (qt * 64 == it * 64);
      // (for this schedule diag is simply it == qt)
#pragma unroll
      for (int cb = 0; cb < 4; ++cb)
#pragma unroll
        for (int r = 0; r < 4; ++r) sc[cb][r] = accs[cb][r];
      if (it == qt) {
#pragma unroll
        for (int cb = 0; cb < 4; ++cb)
#pragma unroll
          for (int r = 0; r < 4; ++r) {
            const int key = it * 64 + cb * 16 + l15;
            const int qr = qw + l4 * 4 + r;
            if (key > qr) sc[cb][r] = -1e30f;
          }
      }
      (void)diag;
      // ---- online softmax over 64 keys (exp2 domain) ----
      float mx[4];
#pragma unroll
      for (int r = 0; r < 4; ++r)
        mx[r] = fmaxf(fmaxf(sc[0][r], sc[1][r]), fmaxf(sc[2][r], sc[3][r]));
#pragma unroll
      for (int off = 1; off <= 8; off <<= 1)
#pragma unroll
        for (int r = 0; r < 4; ++r) mx[r] = fmaxf(mx[r], __shfl_xor(mx[r], off));
      float corr[4];
#pragma unroll
      for (int r = 0; r < 4; ++r) {
        const float mn = fmaxf(m_run[r], mx[r]);
        corr[r] = __builtin_amdgcn_exp2f(m_run[r] - mn);
        m_run[r] = mn;
      }
      float p[4][4];
      float rs[4] = {0.f, 0.f, 0.f, 0.f};
#pragma unroll
      for (int cb = 0; cb < 4; ++cb)
#pragma unroll
        for (int r = 0; r < 4; ++r) {
          p[cb][r] = __builtin_amdgcn_exp2f(sc[cb][r] - m_run[r]);
          rs[r] += p[cb][r];
        }
#pragma unroll
      for (int off = 1; off <= 8; off <<= 1)
#pragma unroll
        for (int r = 0; r < 4; ++r) rs[r] += __shfl_xor(rs[r], off);
#pragma unroll
      for (int r = 0; r < 4; ++r) l_run[r] = l_run[r] * corr[r] + rs[r];
#pragma unroll
      for (int db = 0; db < 4; ++db)
#pragma unroll
        for (int r = 0; r < 4; ++r) acc_o[db][r] *= corr[r];
      // ---- P: C-layout -> per-wave LDS -> A-layout (wave-local, no barrier) ----
#pragma unroll
      for (int cb = 0; cb < 4; ++cb)
#pragma unroll
        for (int r = 0; r < 4; ++r)
          Ps[w][(l4 * 4 + r) * 72 + cb * 16 + l15] = f2bf(p[cb][r]);
      asm volatile("s_waitcnt lgkmcnt(0)" ::: "memory");
      const bf16x8 pa0 = *(const bf16x8*)&Ps[w][l15 * 72 + l4 * 8];
      const bf16x8 pa1 = *(const bf16x8*)&Ps[w][l15 * 72 + 32 + l4 * 8];
      // ---- O += P V (swizzled ds_read of Vs) ----
#pragma unroll
      for (int db = 0; db < 4; ++db) {
        const int row = db * 16 + l15;
        const bf16x8 vf0 = *(const bf16x8*)&VsB[row * 64 + ((l4 ^ sw) * 8)];
        const bf16x8 vf1 = *(const bf16x8*)&VsB[row * 64 + (((l4 + 4) ^ sw) * 8)];
        acc_o[db] = __builtin_amdgcn_mfma_f32_16x16x32_bf16(pa0, vf0, acc_o[db], 0, 0, 0);
        acc_o[db] = __builtin_amdgcn_mfma_f32_16x16x32_bf16(pa1, vf1, acc_o[db], 0, 0, 0);
      }
      // single barrier: drains prefetch vmcnt + our LDS reads, releases buf
      __syncthreads();
    }
    // ---- epilogue: O / l ----
#pragma unroll
    for (int db = 0; db < 4; ++db) {
      const int col = h * DH + db * 16 + l15;
#pragma unroll
      for (int r = 0; r < 4; ++r) {
        const int row = b * S + qw + l4 * 4 + r;
        O[(size_t)row * D + col] = f2bf(acc_o[db][r] / l_run[r]);
      }
    }
  }
}

// ---------------- launch ----------------
extern "C" void kernel_launch(void* const* d_in, const int* in_sizes, int n_in,
                              void* d_out, int out_size, void* d_ws, size_t ws_size,
                              hipStream_t stream) {
  (void)in_sizes; (void)n_in; (void)out_size;
  const float* x   = (const float*)d_in[0];
  const float* wts = (const float*)d_in[1];
  const float* Wq  = (const float*)d_in[2];
  const float* bq  = (const float*)d_in[3];
  const float* Wk  = (const float*)d_in[4];
  const float* bk  = (const float*)d_in[5];
  const float* Wv  = (const float*)d_in[6];
  const float* bv  = (const float*)d_in[7];
  const float* Wo  = (const float*)d_in[8];
  const float* bo  = (const float*)d_in[9];
  float* out = (float*)d_out;

  if (ws_size < 58724352) return;  // need ~56 MB scratch

  char* ws = (char*)d_ws;
  u16* xbf  = (u16*)(ws + 0);          // [4096,1024] bf16
  u16* qbf  = (u16*)(ws + 8388608);
  u16* kbf  = (u16*)(ws + 16777216);
  u16* vbf  = (u16*)(ws + 25165824);
  u16* vt   = (u16*)(ws + 33554432);   // [B,H,DH,S] bf16
  u16* attn = (u16*)(ws + 41943040);   // [4096,1024] bf16
  u16* wqkv = (u16*)(ws + 50331648);   // [3072,1024] bf16 (Wq|Wk|Wv)
  u16* wob  = (u16*)(ws + 56623104);   // Weff bf16
  float* beff = (float*)(ws + 58720256);

  cvt_bf16_kernel<<<2048, 256, 0, stream>>>(x, xbf, 1048576);
  cvt_bf16_kernel<<<1024, 256, 0, stream>>>(Wq, wqkv, 262144);
  cvt_bf16_kernel<<<1024, 256, 0, stream>>>(Wk, wqkv + 1048576, 262144);
  cvt_bf16_kernel<<<1024, 256, 0, stream>>>(Wv, wqkv + 2097152, 262144);
  build_weff_kernel<<<1024, 256, 0, stream>>>(wts, Wo, bo, wob, beff);

  gemm_qkv_kernel<<<dim3(24, 32), 256, 0, stream>>>(xbf, wqkv, bq, bk, bv,
                                                    qbf, kbf, vbf);
  transpose_v_kernel<<<dim3(32, 32), 256, 0, stream>>>(vbf, vt);
  flash_kernel<<<dim3(16, 32), 256, 0, stream>>>(qbf, kbf, vt, attn);
  gemm_bt_kernel<float><<<dim3(8, 32), 256, 0, stream>>>(
      attn, wob, beff, out, 4096, 1024, 1024);
}

// Round 3
// 137.274 us; speedup vs baseline: 1.7624x; 1.1138x over previous
//
#include <hip/hip_runtime.h>

// MultiheadAttention: B=2, S=2048, D=1024, H=16, DH=64, NF=4
// Pipeline:
//   1. cvt x -> bf16; cvt Wq|Wk|Wv -> one contiguous [3072,1024] bf16
//   2. Weff = sum_f w[f]*Wout[f] -> bf16 ; beff = w @ bout -> f32
//   3. qkv = x @ Wqkv^T + b (2-phase dbuf MFMA GEMM; q pre-scaled log2e/8)
//   4. vt = per-head transpose of v  ([B,H,DH,S])
//   5. flash attention: 8-wave blocks, 2 q-tiles share one KV stream,
//      KV-split for long tiles + combine pass, swapped QK^T softmax
//   6. out = attn @ Weff^T + beff  (2-phase dbuf, f32 output)

typedef unsigned short u16;
typedef __bf16 bf16_t;
typedef bf16_t bf16x8 __attribute__((ext_vector_type(8)));
typedef bf16_t bf16x4 __attribute__((ext_vector_type(4)));
typedef float f32x4 __attribute__((ext_vector_type(4)));
typedef u16 u16x8 __attribute__((ext_vector_type(8)));
typedef u16 u16x4 __attribute__((ext_vector_type(4)));

#define DEV __device__ __forceinline__

DEV u16 f2bf(float f) {  // round-to-nearest-even f32 -> bf16
  unsigned u = __float_as_uint(f);
  u += 0x7FFFu + ((u >> 16) & 1u);
  return (u16)(u >> 16);
}

DEV void async_ld16(const void* g, void* lds_wave_uniform) {
  // dst is wave-uniform base; HW writes base + lane*16. Global src is per-lane.
  __builtin_amdgcn_global_load_lds(
      (const __attribute__((address_space(1))) void*)g,
      (__attribute__((address_space(3))) void*)lds_wave_uniform, 16, 0, 0);
}

// ---------------- f32 -> bf16 conversion ----------------
__global__ __launch_bounds__(256) void cvt_bf16_kernel(
    const float* __restrict__ in, u16* __restrict__ out, int n4) {
  int i = blockIdx.x * blockDim.x + threadIdx.x;
  const int stride = gridDim.x * blockDim.x;
  for (; i < n4; i += stride) {
    const float4 v = ((const float4*)in)[i];
    u16x4 o;
    o[0] = f2bf(v.x); o[1] = f2bf(v.y); o[2] = f2bf(v.z); o[3] = f2bf(v.w);
    ((u16x4*)out)[i] = o;
  }
}

// ---------------- Weff = sum_f w[f]*Wout[f]; beff = w @ bout ----------------
__global__ __launch_bounds__(256) void build_weff_kernel(
    const float* __restrict__ w4, const float* __restrict__ Wout,
    const float* __restrict__ bout, u16* __restrict__ Weff,
    float* __restrict__ beff) {
  constexpr int DD4 = 262144;  // (1024*1024)/4
  const int i = blockIdx.x * blockDim.x + threadIdx.x;
  if (i >= DD4) return;
  const float w0 = w4[0], w1 = w4[1], w2 = w4[2], w3 = w4[3];
  const float4* W = (const float4*)Wout;
  const float4 a = W[i], b1 = W[DD4 + i], b2 = W[2 * DD4 + i], b3 = W[3 * DD4 + i];
  u16x4 o;
  o[0] = f2bf(w0 * a.x + w1 * b1.x + w2 * b2.x + w3 * b3.x);
  o[1] = f2bf(w0 * a.y + w1 * b1.y + w2 * b2.y + w3 * b3.y);
  o[2] = f2bf(w0 * a.z + w1 * b1.z + w2 * b2.z + w3 * b3.z);
  o[3] = f2bf(w0 * a.w + w1 * b1.w + w2 * b2.w + w3 * b3.w);
  ((u16x4*)Weff)[i] = o;
  if (i < 256) {  // beff: 1024 floats = 256 float4
    const float4* B4 = (const float4*)bout;
    const float4 ba = B4[i], c1 = B4[256 + i], c2 = B4[512 + i], c3 = B4[768 + i];
    float4 ob;
    ob.x = w0 * ba.x + w1 * c1.x + w2 * c2.x + w3 * c3.x;
    ob.y = w0 * ba.y + w1 * c1.y + w2 * c2.y + w3 * c3.y;
    ob.z = w0 * ba.z + w1 * c1.z + w2 * c2.z + w3 * c3.z;
    ob.w = w0 * ba.w + w1 * c1.w + w2 * c2.w + w3 * c3.w;
    ((float4*)beff)[i] = ob;
  }
}

// ---------------- generic GEMM: C[M,N] = A[M,K] @ Bw[N,K]^T + bias ----------------
// 128x128 tile, BK=32, 4 waves (2x2), 2-phase double-buffered staging.
template <typename OutT>
__global__ __launch_bounds__(256) void gemm_bt_kernel(
    const u16* __restrict__ A, const u16* __restrict__ Bw,
    const float* __restrict__ bias, OutT* __restrict__ C, int M, int N, int K) {
  constexpr int BM = 128, BK = 32;
  __shared__ u16 As[2][BM * BK];
  __shared__ u16 Bs[2][BM * BK];
  const int tid = threadIdx.x;
  const int w = tid >> 6, lane = tid & 63;
  const int l15 = lane & 15, l4 = lane >> 4;
  const int wr = w >> 1, wc = w & 1;
  const long m0 = (long)blockIdx.y * BM, n0 = (long)blockIdx.x * BM;

  const int sr = (tid * 16) >> 6;          // staging row for is=0 chunk
  const int sc = ((tid * 16) & 63) >> 1;   // staging col element

  auto stage = [&](int buf, int kt) {
#pragma unroll
    for (int is = 0; is < 2; ++is) {
      const int r = sr + is * 64;
      async_ld16(A + (m0 + r) * K + kt + sc, &As[buf][w * 512 + is * 2048]);
      async_ld16(Bw + (n0 + r) * K + kt + sc, &Bs[buf][w * 512 + is * 2048]);
    }
  };

  f32x4 acc[4][4] = {};
  stage(0, 0);
  __syncthreads();
  const int nt = K / BK;
  for (int t = 0; t < nt; ++t) {
    const int buf = t & 1;
    if (t + 1 < nt) stage(buf ^ 1, (t + 1) * BK);
    bf16x8 af[4], bfrag[4];
#pragma unroll
    for (int i = 0; i < 4; ++i) {
      af[i] = *(const bf16x8*)&As[buf][(wr * 64 + i * 16 + l15) * BK + l4 * 8];
      bfrag[i] = *(const bf16x8*)&Bs[buf][(wc * 64 + i * 16 + l15) * BK + l4 * 8];
    }
#pragma unroll
    for (int i = 0; i < 4; ++i)
#pragma unroll
      for (int j = 0; j < 4; ++j)
        acc[i][j] = __builtin_amdgcn_mfma_f32_16x16x32_bf16(af[i], bfrag[j],
                                                            acc[i][j], 0, 0, 0);
    __syncthreads();
  }

#pragma unroll
  for (int i = 0; i < 4; ++i) {
    const long row0 = m0 + wr * 64 + i * 16 + l4 * 4;
#pragma unroll
    for (int j = 0; j < 4; ++j) {
      const long col = n0 + wc * 64 + j * 16 + l15;
      const float bb = bias[col];
#pragma unroll
      for (int r = 0; r < 4; ++r) {
        const float v = acc[i][j][r] + bb;
        if constexpr (sizeof(OutT) == 2)
          C[(row0 + r) * N + col] = (OutT)f2bf(v);
        else
          C[(row0 + r) * N + col] = (OutT)v;
      }
    }
  }
}

// ---------------- fused QKV GEMM: [4096,1024] x [3072,1024]^T ----------------
// Q output pre-scaled by log2e / sqrt(DH) so flash softmax can use exp2.
__global__ __launch_bounds__(256) void gemm_qkv_kernel(
    const u16* __restrict__ A, const u16* __restrict__ Bw,
    const float* __restrict__ bq, const float* __restrict__ bk,
    const float* __restrict__ bv, u16* __restrict__ qo, u16* __restrict__ ko,
    u16* __restrict__ vo) {
  constexpr int K = 1024, BK = 32;
  __shared__ u16 As[2][128 * BK];
  __shared__ u16 Bs[2][128 * BK];
  const int tid = threadIdx.x;
  const int w = tid >> 6, lane = tid & 63;
  const int l15 = lane & 15, l4 = lane >> 4;
  const int wr = w >> 1, wc = w & 1;
  const long m0 = (long)blockIdx.y * 128, n0 = (long)blockIdx.x * 128;
  const int seg = blockIdx.x >> 3;  // 0=q 1=k 2=v
  const float* bias = seg == 0 ? bq : (seg == 1 ? bk : bv);
  u16* outp = seg == 0 ? qo : (seg == 1 ? ko : vo);
  const float scale = seg == 0 ? 0.18033688011112042f : 1.0f;  // log2e/8

  const int sr = (tid * 16) >> 6;
  const int sc = ((tid * 16) & 63) >> 1;

  auto stage = [&](int buf, int kt) {
#pragma unroll
    for (int is = 0; is < 2; ++is) {
      const int r = sr + is * 64;
      async_ld16(A + (m0 + r) * K + kt + sc, &As[buf][w * 512 + is * 2048]);
      async_ld16(Bw + (n0 + r) * K + kt + sc, &Bs[buf][w * 512 + is * 2048]);
    }
  };

  f32x4 acc[4][4] = {};
  stage(0, 0);
  __syncthreads();
  const int nt = K / BK;
  for (int t = 0; t < nt; ++t) {
    const int buf = t & 1;
    if (t + 1 < nt) stage(buf ^ 1, (t + 1) * BK);
    bf16x8 af[4], bfrag[4];
#pragma unroll
    for (int i = 0; i < 4; ++i) {
      af[i] = *(const bf16x8*)&As[buf][(wr * 64 + i * 16 + l15) * BK + l4 * 8];
      bfrag[i] = *(const bf16x8*)&Bs[buf][(wc * 64 + i * 16 + l15) * BK + l4 * 8];
    }
#pragma unroll
    for (int i = 0; i < 4; ++i)
#pragma unroll
      for (int j = 0; j < 4; ++j)
        acc[i][j] = __builtin_amdgcn_mfma_f32_16x16x32_bf16(af[i], bfrag[j],
                                                            acc[i][j], 0, 0, 0);
    __syncthreads();
  }

#pragma unroll
  for (int i = 0; i < 4; ++i) {
    const long row0 = m0 + wr * 64 + i * 16 + l4 * 4;
#pragma unroll
    for (int j = 0; j < 4; ++j) {
      const long col = n0 + wc * 64 + j * 16 + l15 - (long)seg * 1024;
      const float bb = bias[col];
#pragma unroll
      for (int r = 0; r < 4; ++r)
        outp[(row0 + r) * 1024 + col] = f2bf((acc[i][j][r] + bb) * scale);
    }
  }
}

// ---------------- per-head V transpose: Vt[b,h,d,s] = V[b*s, h*64+d] ----------------
__global__ __launch_bounds__(256) void transpose_v_kernel(
    const u16* __restrict__ V, u16* __restrict__ Vt) {
  constexpr int S = 2048, D = 1024, DH = 64;
  __shared__ u16 T[64 * 72];
  const int tid = threadIdx.x;
  const int bh = blockIdx.y, b = bh >> 4, h = bh & 15;
  const int s0 = blockIdx.x * 64;
#pragma unroll
  for (int is = 0; is < 2; ++is) {
    const int sl = tid + is * 256;
    const int r = sl >> 3, c0 = (sl & 7) * 8;
    *(u16x8*)&T[r * 72 + c0] =
        *(const u16x8*)(V + (size_t)(b * S + s0 + r) * D + h * DH + c0);
  }
  __syncthreads();
#pragma unroll
  for (int is = 0; is < 2; ++is) {
    const int sl = tid + is * 256;
    const int d = sl >> 3, k0 = (sl & 7) * 8;
    u16x8 o;
#pragma unroll
    for (int j = 0; j < 8; ++j) o[j] = T[(k0 + j) * 72 + d];
    *(u16x8*)(Vt + (size_t)(bh * DH + d) * S + s0 + k0) = o;
  }
}

// ---------------- causal flash attention v3 ----------------
// 512 threads = 8 waves covering q-tiles (2i, 2i+1): one shared KV stream.
// blockIdx.x < 8: i = x, full kv range [0, 2i+2), writes final output.
// blockIdx.x >= 8: i = 8 + (x-8)/2, seg = (x-8)&1, kv range split in two
//   balanced halves; writes bf16 partials (acc, m, l) combined later.
// Swapped QK^T: accs = mfma(K, Q) -> lane holds 16 keys of ONE q-row
//   => 2-shfl row reduce, packed b64 P writes, XOR-swizzled Ps.
__global__ __launch_bounds__(512, 6) void flash_kernel(
    const u16* __restrict__ Q, const u16* __restrict__ Kg,
    const u16* __restrict__ Vt, u16* __restrict__ O,
    u16* __restrict__ accP, float* __restrict__ mP, float* __restrict__ lP) {
  constexpr int S = 2048, D = 1024, DH = 64;
  __shared__ u16 Ks[2][4096];  // [key][feat], XOR-swizzled 16B chunks
  __shared__ u16 Vs[2][4096];  // [d][key], XOR-swizzled 16B chunks
  __shared__ u16 Ps[8192];     // 8 waves x [16 q][64 key], XOR-swizzled
  const int tid = threadIdx.x;
  const int w = tid >> 6, lane = tid & 63;
  const int l15 = lane & 15, l4 = lane >> 4;
  const int bh = blockIdx.y, b = bh >> 4, h = bh & 15;
  const int x = blockIdx.x;
  int i, kvlo, kvhi, seg;
  if (x < 8) {
    i = x; seg = -1; kvlo = 0; kvhi = 2 * i + 2;
  } else {
    const int idx = x - 8;
    i = 8 + (idx >> 1); seg = idx & 1;
    kvlo = seg ? (i + 1) : 0;
    kvhi = seg ? (2 * i + 2) : (i + 1);
  }
  const int qw = 128 * i + w * 16;  // wave's first q row within bh
  const int qtile = qw >> 6;

  const u16* Kbh = Kg + (size_t)b * S * D + h * DH;
  const u16* Vbh = Vt + (size_t)bh * DH * S;

  // staging: 512 threads x 16B cover one 64x64 bf16 tile; inverse-swizzled src
  const int srow = tid >> 3;
  const int scol = ((tid & 7) ^ (srow & 7)) * 8;
  const int sw = l15 & 7;

  // Q fragment (B-operand): B[col=q=l15][k=l4*8+j]; prescaled by log2e/8
  bf16x8 qf[2];
  {
    const u16* qp = Q + (size_t)(b * S + qw + l15) * D + h * DH + l4 * 8;
    qf[0] = *(const bf16x8*)qp;
    qf[1] = *(const bf16x8*)(qp + 32);
  }

  f32x4 acc_o[4] = {};
  float m_run = -3e38f, l_run = 0.f;  // per-lane stats for q = qw + l15

  // prologue: stage tile kvlo into buf 0
  async_ld16(Kbh + (size_t)(kvlo * 64 + srow) * D + scol, &Ks[0][w * 512]);
  async_ld16(Vbh + (size_t)srow * S + kvlo * 64 + scol, &Vs[0][w * 512]);
  __syncthreads();

  for (int it = kvlo; it < kvhi; ++it) {
    const int buf = (it - kvlo) & 1;
    if (it + 1 < kvhi) {  // async prefetch next tile (drained at barrier)
      async_ld16(Kbh + (size_t)((it + 1) * 64 + srow) * D + scol,
                 &Ks[buf ^ 1][w * 512]);
      async_ld16(Vbh + (size_t)srow * S + (it + 1) * 64 + scol,
                 &Vs[buf ^ 1][w * 512]);
    }
    if (it <= qtile) {
      // ---- S^T = K Q^T : lane holds S[key = it*64+cb*16+l4*4+r][q = qw+l15]
      f32x4 accs[4] = {};
#pragma unroll
      for (int cb = 0; cb < 4; ++cb) {
        const int row = cb * 16 + l15;
        const bf16x8 kf0 = *(const bf16x8*)&Ks[buf][row * 64 + ((l4 ^ sw) * 8)];
        const bf16x8 kf1 =
            *(const bf16x8*)&Ks[buf][row * 64 + (((l4 + 4) ^ sw) * 8)];
        accs[cb] =
            __builtin_amdgcn_mfma_f32_16x16x32_bf16(kf0, qf[0], accs[cb], 0, 0, 0);
        accs[cb] =
            __builtin_amdgcn_mfma_f32_16x16x32_bf16(kf1, qf[1], accs[cb], 0, 0, 0);
      }
      // ---- causal mask (diag tile only) + local max over lane's 16 keys ----
      const bool diag = (it == qtile);
      float mx = -3e38f;
#pragma unroll
      for (int cb = 0; cb < 4; ++cb)
#pragma unroll
        for (int r = 0; r < 4; ++r) {
          float s_ = accs[cb][r];
          if (diag && (it * 64 + cb * 16 + l4 * 4 + r > qw + l15)) s_ = -3e38f;
          accs[cb][r] = s_;
          mx = fmaxf(mx, s_);
        }
      // ---- row reduce across the 4 lane-groups holding this q ----
      mx = fmaxf(mx, __shfl_xor(mx, 16));
      mx = fmaxf(mx, __shfl_xor(mx, 32));
      const float mn = fmaxf(m_run, mx);
      const float corr = __builtin_amdgcn_exp2f(m_run - mn);
      m_run = mn;
      float rs = 0.f;
#pragma unroll
      for (int cb = 0; cb < 4; ++cb)
#pragma unroll
        for (int r = 0; r < 4; ++r) {
          const float pv = __builtin_amdgcn_exp2f(accs[cb][r] - mn);
          accs[cb][r] = pv;
          rs += pv;
        }
      rs += __shfl_xor(rs, 16);
      rs += __shfl_xor(rs, 32);
      l_run = l_run * corr + rs;
      // ---- broadcast corr to PV accumulator rows (q = l4*4 + r) ----
      float cq[4];
#pragma unroll
      for (int r = 0; r < 4; ++r) cq[r] = __shfl(corr, l4 * 4 + r, 64);
#pragma unroll
      for (int db = 0; db < 4; ++db)
#pragma unroll
        for (int r = 0; r < 4; ++r) acc_o[db][r] *= cq[r];
      // ---- pack P (4 consecutive keys/lane) -> swizzled per-wave LDS ----
#pragma unroll
      for (int cb = 0; cb < 4; ++cb) {
        bf16x4 pk = {(bf16_t)accs[cb][0], (bf16_t)accs[cb][1],
                     (bf16_t)accs[cb][2], (bf16_t)accs[cb][3]};
        const int chunk = (2 * cb + (l4 >> 1)) ^ sw;
        *(bf16x4*)&Ps[w * 1024 + l15 * 64 + chunk * 8 + (l4 & 1) * 4] = pk;
      }
      // ---- read P as A-fragment: P[q=l15][keys l4*8..] ----
      bf16x8 pa[2];
#pragma unroll
      for (int mf = 0; mf < 2; ++mf) {
        const int chunk = (mf * 4 + l4) ^ sw;
        pa[mf] = *(const bf16x8*)&Ps[w * 1024 + l15 * 64 + chunk * 8];
      }
      // ---- O += P V ----
#pragma unroll
      for (int db = 0; db < 4; ++db) {
        const int row = db * 16 + l15;
        const bf16x8 vf0 = *(const bf16x8*)&Vs[buf][row * 64 + ((l4 ^ sw) * 8)];
        const bf16x8 vf1 =
            *(const bf16x8*)&Vs[buf][row * 64 + (((l4 + 4) ^ sw) * 8)];
        acc_o[db] =
            __builtin_amdgcn_mfma_f32_16x16x32_bf16(pa[0], vf0, acc_o[db], 0, 0, 0);
        acc_o[db] =
            __builtin_amdgcn_mfma_f32_16x16x32_bf16(pa[1], vf1, acc_o[db], 0, 0, 0);
      }
    }
    __syncthreads();  // releases buf, drains prefetch
  }

  if (seg < 0) {
    // final output: O[q][d] / l
    float lq[4];
#pragma unroll
    for (int r = 0; r < 4; ++r) lq[r] = __shfl(l_run, l4 * 4 + r, 64);
    bf16_t* Ob = (bf16_t*)O;
#pragma unroll
    for (int db = 0; db < 4; ++db) {
      const int col = h * DH + db * 16 + l15;
#pragma unroll
      for (int r = 0; r < 4; ++r)
        Ob[(size_t)(b * S + qw + l4 * 4 + r) * D + col] =
            (bf16_t)(acc_o[db][r] / lq[r]);
    }
  } else {
    // partials for rows 1024..2047 of this bh
    const size_t base = (size_t)seg * 32768 + (size_t)bh * 1024 + (qw - 1024);
    bf16_t* aP = (bf16_t*)accP;
#pragma unroll
    for (int db = 0; db < 4; ++db)
#pragma unroll
      for (int r = 0; r < 4; ++r)
        aP[(base + l4 * 4 + r) * 64 + db * 16 + l15] = (bf16_t)acc_o[db][r];
    if (l4 == 0) {
      mP[base + l15] = m_run;
      lP[base + l15] = l_run;
    }
  }
}

// ---------------- combine split-KV partials ----------------
__global__ __launch_bounds__(256) void combine_kernel(
    const u16* __restrict__ accP, const float* __restrict__ mP,
    const float* __restrict__ lP, u16* __restrict__ O) {
  const int id = blockIdx.x * 256 + threadIdx.x;  // 262144 tasks
  const int row = id >> 3;                        // 0..32767
  const int c0 = (id & 7) * 8;
  const float m0 = mP[row], m1 = mP[32768 + row];
  const float l0 = lP[row], l1 = lP[32768 + row];
  const float M = fmaxf(m0, m1);
  const float e0 = __builtin_amdgcn_exp2f(m0 - M);
  const float e1 = __builtin_amdgcn_exp2f(m1 - M);
  const float inv = 1.f / (l0 * e0 + l1 * e1);
  const bf16_t* aP = (const bf16_t*)accP;
  const bf16x8 a0 = *(const bf16x8*)&aP[(size_t)row * 64 + c0];
  const bf16x8 a1 = *(const bf16x8*)&aP[(size_t)(32768 + row) * 64 + c0];
  const int bh = row >> 10, s = 1024 + (row & 1023);
  const int b = bh >> 4, h = bh & 15;
  bf16_t* out = (bf16_t*)O + (size_t)(b * 2048 + s) * 1024 + h * 64 + c0;
  bf16x8 o;
#pragma unroll
  for (int j = 0; j < 8; ++j)
    o[j] = (bf16_t)(((float)a0[j] * e0 + (float)a1[j] * e1) * inv);
  *(bf16x8*)out = o;
}

// ---------------- launch ----------------
extern "C" void kernel_launch(void* const* d_in, const int* in_sizes, int n_in,
                              void* d_out, int out_size, void* d_ws, size_t ws_size,
                              hipStream_t stream) {
  (void)in_sizes; (void)n_in; (void)out_size;
  const float* x   = (const float*)d_in[0];
  const float* wts = (const float*)d_in[1];
  const float* Wq  = (const float*)d_in[2];
  const float* bq  = (const float*)d_in[3];
  const float* Wk  = (const float*)d_in[4];
  const float* bk  = (const float*)d_in[5];
  const float* Wv  = (const float*)d_in[6];
  const float* bv  = (const float*)d_in[7];
  const float* Wo  = (const float*)d_in[8];
  const float* bo  = (const float*)d_in[9];
  float* out = (float*)d_out;

  if (ws_size < 58724352) return;  // need ~56 MB scratch

  char* ws = (char*)d_ws;
  u16* xbf  = (u16*)(ws + 0);          // [4096,1024] bf16 (reused as accP later)
  u16* qbf  = (u16*)(ws + 8388608);
  u16* kbf  = (u16*)(ws + 16777216);
  u16* vbf  = (u16*)(ws + 25165824);
  u16* vt   = (u16*)(ws + 33554432);   // [B,H,DH,S] bf16
  u16* attn = (u16*)(ws + 41943040);   // [4096,1024] bf16
  u16* wqkv = (u16*)(ws + 50331648);   // [3072,1024] bf16 (reused as mP/lP later)
  u16* wob  = (u16*)(ws + 56623104);   // Weff bf16
  float* beff = (float*)(ws + 58720256);

  // overlays (dead after gemm_qkv):
  u16* accP = xbf;                       // 2 x 32768 x 64 bf16 = 8 MB
  float* mP = (float*)(ws + 50331648);   // 2 x 32768 f32
  float* lP = mP + 65536;

  cvt_bf16_kernel<<<2048, 256, 0, stream>>>(x, xbf, 1048576);
  cvt_bf16_kernel<<<1024, 256, 0, stream>>>(Wq, wqkv, 262144);
  cvt_bf16_kernel<<<1024, 256, 0, stream>>>(Wk, wqkv + 1048576, 262144);
  cvt_bf16_kernel<<<1024, 256, 0, stream>>>(Wv, wqkv + 2097152, 262144);
  build_weff_kernel<<<1024, 256, 0, stream>>>(wts, Wo, bo, wob, beff);

  gemm_qkv_kernel<<<dim3(24, 32), 256, 0, stream>>>(xbf, wqkv, bq, bk, bv,
                                                    qbf, kbf, vbf);
  transpose_v_kernel<<<dim3(32, 32), 256, 0, stream>>>(vbf, vt);
  flash_kernel<<<dim3(24, 32), 512, 0, stream>>>(qbf, kbf, vt, attn,
                                                 accP, mP, lP);
  combine_kernel<<<1024, 256, 0, stream>>>(accP, mP, lP, attn);
  gemm_bt_kernel<float><<<dim3(8, 32), 256, 0, stream>>>(
      attn, wob, beff, out, 4096, 1024, 1024);
}

// Round 4
// 126.656 us; speedup vs baseline: 1.9101x; 1.0838x over previous
//
#include <hip/hip_runtime.h>

// MultiheadAttention: B=2, S=2048, D=1024, H=16, DH=64, NF=4
// Pipeline:
//   1. cvt x -> bf16; cvt Wq|Wk|Wv -> one contiguous [3072,1024] bf16 (fused)
//   2. Weff = sum_f w[f]*Wout[f] -> bf16 ; beff = w @ bout -> f32
//   3. qkv = x @ Wqkv^T + b (2-phase dbuf MFMA GEMM, LDS-coalesced bf16 epilogue)
//   4. vt = per-head transpose of v  ([B,H,DH,S])
//   5. flash attention: 8-wave blocks, 2 q-tiles share one KV stream,
//      KV-split + combine, swapped QK^T, defer-max, heavy-blocks-first,
//      LDS-coalesced output writes
//   6. out = attn @ Weff^T + beff  (2-phase dbuf, f32 output)

typedef unsigned short u16;
typedef __bf16 bf16_t;
typedef bf16_t bf16x8 __attribute__((ext_vector_type(8)));
typedef bf16_t bf16x4 __attribute__((ext_vector_type(4)));
typedef float f32x4 __attribute__((ext_vector_type(4)));
typedef u16 u16x8 __attribute__((ext_vector_type(8)));
typedef u16 u16x4 __attribute__((ext_vector_type(4)));

#define DEV __device__ __forceinline__

DEV u16 f2bf(float f) {  // round-to-nearest-even f32 -> bf16
  unsigned u = __float_as_uint(f);
  u += 0x7FFFu + ((u >> 16) & 1u);
  return (u16)(u >> 16);
}

DEV void async_ld16(const void* g, void* lds_wave_uniform) {
  // dst is wave-uniform base; HW writes base + lane*16. Global src is per-lane.
  __builtin_amdgcn_global_load_lds(
      (const __attribute__((address_space(1))) void*)g,
      (__attribute__((address_space(3))) void*)lds_wave_uniform, 16, 0, 0);
}

// ---------------- f32 -> bf16 conversion (x) ----------------
__global__ __launch_bounds__(256) void cvt_bf16_kernel(
    const float* __restrict__ in, u16* __restrict__ out, int n4) {
  int i = blockIdx.x * blockDim.x + threadIdx.x;
  const int stride = gridDim.x * blockDim.x;
  for (; i < n4; i += stride) {
    const float4 v = ((const float4*)in)[i];
    u16x4 o;
    o[0] = f2bf(v.x); o[1] = f2bf(v.y); o[2] = f2bf(v.z); o[3] = f2bf(v.w);
    ((u16x4*)out)[i] = o;
  }
}

// ---------------- fused Wq|Wk|Wv -> bf16 ----------------
__global__ __launch_bounds__(256) void cvt3_bf16_kernel(
    const float* __restrict__ a, const float* __restrict__ b,
    const float* __restrict__ c, u16* __restrict__ out) {
  const int i = blockIdx.x * 256 + threadIdx.x;  // 786432 float4 tasks
  const int which = i >> 18;                     // / 262144
  const int j = i & 262143;
  const float* src = which == 0 ? a : (which == 1 ? b : c);
  const float4 v = ((const float4*)src)[j];
  u16x4 o;
  o[0] = f2bf(v.x); o[1] = f2bf(v.y); o[2] = f2bf(v.z); o[3] = f2bf(v.w);
  ((u16x4*)out)[i] = o;
}

// ---------------- Weff = sum_f w[f]*Wout[f]; beff = w @ bout ----------------
__global__ __launch_bounds__(256) void build_weff_kernel(
    const float* __restrict__ w4, const float* __restrict__ Wout,
    const float* __restrict__ bout, u16* __restrict__ Weff,
    float* __restrict__ beff) {
  constexpr int DD4 = 262144;  // (1024*1024)/4
  const int i = blockIdx.x * blockDim.x + threadIdx.x;
  if (i >= DD4) return;
  const float w0 = w4[0], w1 = w4[1], w2 = w4[2], w3 = w4[3];
  const float4* W = (const float4*)Wout;
  const float4 a = W[i], b1 = W[DD4 + i], b2 = W[2 * DD4 + i], b3 = W[3 * DD4 + i];
  u16x4 o;
  o[0] = f2bf(w0 * a.x + w1 * b1.x + w2 * b2.x + w3 * b3.x);
  o[1] = f2bf(w0 * a.y + w1 * b1.y + w2 * b2.y + w3 * b3.y);
  o[2] = f2bf(w0 * a.z + w1 * b1.z + w2 * b2.z + w3 * b3.z);
  o[3] = f2bf(w0 * a.w + w1 * b1.w + w2 * b2.w + w3 * b3.w);
  ((u16x4*)Weff)[i] = o;
  if (i < 256) {  // beff: 1024 floats = 256 float4
    const float4* B4 = (const float4*)bout;
    const float4 ba = B4[i], c1 = B4[256 + i], c2 = B4[512 + i], c3 = B4[768 + i];
    float4 ob;
    ob.x = w0 * ba.x + w1 * c1.x + w2 * c2.x + w3 * c3.x;
    ob.y = w0 * ba.y + w1 * c1.y + w2 * c2.y + w3 * c3.y;
    ob.z = w0 * ba.z + w1 * c1.z + w2 * c2.z + w3 * c3.z;
    ob.w = w0 * ba.w + w1 * c1.w + w2 * c2.w + w3 * c3.w;
    ((float4*)beff)[i] = ob;
  }
}

// ---------------- out GEMM: C[M,N](f32) = A[M,K] @ Bw[N,K]^T + bias ----------------
// 128x128 tile, BK=32, 4 waves (2x2), 2-phase double-buffered staging.
__global__ __launch_bounds__(256) void gemm_bt_kernel(
    const u16* __restrict__ A, const u16* __restrict__ Bw,
    const float* __restrict__ bias, float* __restrict__ C, int M, int N, int K) {
  constexpr int BM = 128, BK = 32;
  __shared__ u16 As[2][BM * BK];
  __shared__ u16 Bs[2][BM * BK];
  const int tid = threadIdx.x;
  const int w = tid >> 6, lane = tid & 63;
  const int l15 = lane & 15, l4 = lane >> 4;
  const int wr = w >> 1, wc = w & 1;
  const long m0 = (long)blockIdx.y * BM, n0 = (long)blockIdx.x * BM;

  const int sr = (tid * 16) >> 6;          // staging row for is=0 chunk
  const int sc = ((tid * 16) & 63) >> 1;   // staging col element

  auto stage = [&](int buf, int kt) {
#pragma unroll
    for (int is = 0; is < 2; ++is) {
      const int r = sr + is * 64;
      async_ld16(A + (m0 + r) * K + kt + sc, &As[buf][w * 512 + is * 2048]);
      async_ld16(Bw + (n0 + r) * K + kt + sc, &Bs[buf][w * 512 + is * 2048]);
    }
  };

  f32x4 acc[4][4] = {};
  stage(0, 0);
  __syncthreads();
  const int nt = K / BK;
  for (int t = 0; t < nt; ++t) {
    const int buf = t & 1;
    if (t + 1 < nt) stage(buf ^ 1, (t + 1) * BK);
    bf16x8 af[4], bfrag[4];
#pragma unroll
    for (int i = 0; i < 4; ++i) {
      af[i] = *(const bf16x8*)&As[buf][(wr * 64 + i * 16 + l15) * BK + l4 * 8];
      bfrag[i] = *(const bf16x8*)&Bs[buf][(wc * 64 + i * 16 + l15) * BK + l4 * 8];
    }
#pragma unroll
    for (int i = 0; i < 4; ++i)
#pragma unroll
      for (int j = 0; j < 4; ++j)
        acc[i][j] = __builtin_amdgcn_mfma_f32_16x16x32_bf16(af[i], bfrag[j],
                                                            acc[i][j], 0, 0, 0);
    __syncthreads();
  }

#pragma unroll
  for (int i = 0; i < 4; ++i) {
    const long row0 = m0 + wr * 64 + i * 16 + l4 * 4;
#pragma unroll
    for (int j = 0; j < 4; ++j) {
      const long col = n0 + wc * 64 + j * 16 + l15;
      const float bb = bias[col];
#pragma unroll
      for (int r = 0; r < 4; ++r)
        C[(row0 + r) * N + col] = acc[i][j][r] + bb;
    }
  }
}

// ---------------- fused QKV GEMM: [4096,1024] x [3072,1024]^T ----------------
// Q output pre-scaled by log2e/8. LDS-coalesced bf16 epilogue (u16x8 stores).
__global__ __launch_bounds__(256) void gemm_qkv_kernel(
    const u16* __restrict__ A, const u16* __restrict__ Bw,
    const float* __restrict__ bq, const float* __restrict__ bk,
    const float* __restrict__ bv, u16* __restrict__ qo, u16* __restrict__ ko,
    u16* __restrict__ vo) {
  constexpr int K = 1024, BK = 32;
  __shared__ u16 SM[16384];  // 32KB: As[2][4096] | Bs[2][4096]; reused as C tile
  u16* As = SM;
  u16* Bs = SM + 8192;
  const int tid = threadIdx.x;
  const int w = tid >> 6, lane = tid & 63;
  const int l15 = lane & 15, l4 = lane >> 4;
  const int wr = w >> 1, wc = w & 1;
  const long m0 = (long)blockIdx.y * 128, n0 = (long)blockIdx.x * 128;
  const int seg = blockIdx.x >> 3;  // 0=q 1=k 2=v
  const float* bias = seg == 0 ? bq : (seg == 1 ? bk : bv);
  u16* outp = seg == 0 ? qo : (seg == 1 ? ko : vo);
  const float scale = seg == 0 ? 0.18033688011112042f : 1.0f;  // log2e/8

  const int sr = (tid * 16) >> 6;
  const int sc = ((tid * 16) & 63) >> 1;

  auto stage = [&](int buf, int kt) {
#pragma unroll
    for (int is = 0; is < 2; ++is) {
      const int r = sr + is * 64;
      async_ld16(A + (m0 + r) * K + kt + sc, &As[buf * 4096 + w * 512 + is * 2048]);
      async_ld16(Bw + (n0 + r) * K + kt + sc, &Bs[buf * 4096 + w * 512 + is * 2048]);
    }
  };

  f32x4 acc[4][4] = {};
  stage(0, 0);
  __syncthreads();
  const int nt = K / BK;
  for (int t = 0; t < nt; ++t) {
    const int buf = t & 1;
    if (t + 1 < nt) stage(buf ^ 1, (t + 1) * BK);
    bf16x8 af[4], bfrag[4];
#pragma unroll
    for (int i = 0; i < 4; ++i) {
      af[i] = *(const bf16x8*)&As[buf * 4096 + (wr * 64 + i * 16 + l15) * BK + l4 * 8];
      bfrag[i] = *(const bf16x8*)&Bs[buf * 4096 + (wc * 64 + i * 16 + l15) * BK + l4 * 8];
    }
#pragma unroll
    for (int i = 0; i < 4; ++i)
#pragma unroll
      for (int j = 0; j < 4; ++j)
        acc[i][j] = __builtin_amdgcn_mfma_f32_16x16x32_bf16(af[i], bfrag[j],
                                                            acc[i][j], 0, 0, 0);
    __syncthreads();
  }

  // ---- epilogue: acc -> swizzled SM[128][128] -> coalesced u16x8 stores ----
  const long ccol0 = n0 - (long)seg * 1024;
#pragma unroll
  for (int i = 0; i < 4; ++i) {
#pragma unroll
    for (int j = 0; j < 4; ++j) {
      const int colb = wc * 64 + j * 16 + l15;
      const float bb = bias[ccol0 + colb];
#pragma unroll
      for (int r = 0; r < 4; ++r) {
        const int row = wr * 64 + i * 16 + l4 * 4 + r;
        SM[row * 128 + (colb ^ ((row & 15) << 3))] =
            f2bf((acc[i][j][r] + bb) * scale);
      }
    }
  }
  __syncthreads();
#pragma unroll
  for (int p = 0; p < 8; ++p) {
    const int cid = p * 256 + tid;
    const int row = cid >> 4, c = cid & 15;
    const u16x8 vch = *(const u16x8*)&SM[row * 128 + ((c ^ (row & 15)) * 8)];
    *(u16x8*)&outp[(m0 + row) * 1024 + ccol0 + c * 8] = vch;
  }
}

// ---------------- per-head V transpose: Vt[b,h,d,s] = V[b*s, h*64+d] ----------------
__global__ __launch_bounds__(256) void transpose_v_kernel(
    const u16* __restrict__ V, u16* __restrict__ Vt) {
  constexpr int S = 2048, D = 1024, DH = 64;
  __shared__ u16 T[64 * 72];
  const int tid = threadIdx.x;
  const int bh = blockIdx.y, b = bh >> 4, h = bh & 15;
  const int s0 = blockIdx.x * 64;
#pragma unroll
  for (int is = 0; is < 2; ++is) {
    const int sl = tid + is * 256;
    const int r = sl >> 3, c0 = (sl & 7) * 8;
    *(u16x8*)&T[r * 72 + c0] =
        *(const u16x8*)(V + (size_t)(b * S + s0 + r) * D + h * DH + c0);
  }
  __syncthreads();
#pragma unroll
  for (int is = 0; is < 2; ++is) {
    const int sl = tid + is * 256;
    const int d = sl >> 3, k0 = (sl & 7) * 8;
    u16x8 o;
#pragma unroll
    for (int j = 0; j < 8; ++j) o[j] = T[(k0 + j) * 72 + d];
    *(u16x8*)(Vt + (size_t)(bh * DH + d) * S + s0 + k0) = o;
  }
}

// ---------------- causal flash attention v4 ----------------
// 512 threads = 8 waves covering q-tiles (2i, 2i+1): one shared KV stream.
// x' < 8: i = x', full kv range, writes final output.
// x' >= 8: split-KV halves, writes bf16 partials (acc, m, l), combined later.
// Heavy-first remap x' = 23 - blockIdx.x. Swapped QK^T, defer-max (THR=8),
// LDS-coalesced output writes through the per-wave Ps slot.
__global__ __launch_bounds__(512, 6) void flash_kernel(
    const u16* __restrict__ Q, const u16* __restrict__ Kg,
    const u16* __restrict__ Vt, u16* __restrict__ O,
    u16* __restrict__ accP, float* __restrict__ mP, float* __restrict__ lP) {
  constexpr int S = 2048, D = 1024, DH = 64;
  __shared__ u16 Ks[2][4096];  // [key][feat], XOR-swizzled 16B chunks
  __shared__ u16 Vs[2][4096];  // [d][key], XOR-swizzled 16B chunks
  __shared__ u16 Ps[8192];     // 8 waves x [16 q][64 key], XOR-swizzled
  const int tid = threadIdx.x;
  const int w = tid >> 6, lane = tid & 63;
  const int l15 = lane & 15, l4 = lane >> 4;
  const int bh = blockIdx.y, b = bh >> 4, h = bh & 15;
  const int x = 23 - (int)blockIdx.x;  // heavy blocks dispatched first
  int bi, kvlo, kvhi, seg;
  if (x < 8) {
    bi = x; seg = -1; kvlo = 0; kvhi = 2 * bi + 2;
  } else {
    const int idx = x - 8;
    bi = 8 + (idx >> 1); seg = idx & 1;
    kvlo = seg ? (bi + 1) : 0;
    kvhi = seg ? (2 * bi + 2) : (bi + 1);
  }
  const int qw = 128 * bi + w * 16;  // wave's first q row within bh
  const int qtile = qw >> 6;

  const u16* Kbh = Kg + (size_t)b * S * D + h * DH;
  const u16* Vbh = Vt + (size_t)bh * DH * S;

  // staging: 512 threads x 16B cover one 64x64 bf16 tile; inverse-swizzled src
  const int srow = tid >> 3;
  const int scol = ((tid & 7) ^ (srow & 7)) * 8;
  const int sw = l15 & 7;

  // Q fragment (B-operand): B[col=q=l15][k=l4*8+j]; prescaled by log2e/8
  bf16x8 qf[2];
  {
    const u16* qp = Q + (size_t)(b * S + qw + l15) * D + h * DH + l4 * 8;
    qf[0] = *(const bf16x8*)qp;
    qf[1] = *(const bf16x8*)(qp + 32);
  }

  f32x4 acc_o[4] = {};
  float m_run = -3e38f, l_run = 0.f;  // per-lane stats for q = qw + l15

  // prologue: stage tile kvlo into buf 0
  async_ld16(Kbh + (size_t)(kvlo * 64 + srow) * D + scol, &Ks[0][w * 512]);
  async_ld16(Vbh + (size_t)srow * S + kvlo * 64 + scol, &Vs[0][w * 512]);
  __syncthreads();

  for (int it = kvlo; it < kvhi; ++it) {
    const int buf = (it - kvlo) & 1;
    if (it + 1 < kvhi) {  // async prefetch next tile (drained at barrier)
      async_ld16(Kbh + (size_t)((it + 1) * 64 + srow) * D + scol,
                 &Ks[buf ^ 1][w * 512]);
      async_ld16(Vbh + (size_t)srow * S + (it + 1) * 64 + scol,
                 &Vs[buf ^ 1][w * 512]);
    }
    if (it <= qtile) {
      // ---- S^T = K Q^T : lane holds S[key = it*64+cb*16+l4*4+r][q = qw+l15]
      f32x4 accs[4] = {};
#pragma unroll
      for (int cb = 0; cb < 4; ++cb) {
        const int row = cb * 16 + l15;
        const bf16x8 kf0 = *(const bf16x8*)&Ks[buf][row * 64 + ((l4 ^ sw) * 8)];
        const bf16x8 kf1 =
            *(const bf16x8*)&Ks[buf][row * 64 + (((l4 + 4) ^ sw) * 8)];
        accs[cb] =
            __builtin_amdgcn_mfma_f32_16x16x32_bf16(kf0, qf[0], accs[cb], 0, 0, 0);
        accs[cb] =
            __builtin_amdgcn_mfma_f32_16x16x32_bf16(kf1, qf[1], accs[cb], 0, 0, 0);
      }
      // ---- causal mask (diag tile only) + local max over lane's 16 keys ----
      float mx = -3e38f;
      if (it == qtile) {
#pragma unroll
        for (int cb = 0; cb < 4; ++cb)
#pragma unroll
          for (int r = 0; r < 4; ++r) {
            float s_ = accs[cb][r];
            if (it * 64 + cb * 16 + l4 * 4 + r > qw + l15) s_ = -3e38f;
            accs[cb][r] = s_;
            mx = fmaxf(mx, s_);
          }
      } else {
#pragma unroll
        for (int cb = 0; cb < 4; ++cb)
#pragma unroll
          for (int r = 0; r < 4; ++r) mx = fmaxf(mx, accs[cb][r]);
      }
      // ---- row reduce across the 4 lane-groups holding this q ----
      mx = fmaxf(mx, __shfl_xor(mx, 16));
      mx = fmaxf(mx, __shfl_xor(mx, 32));
      // ---- defer-max (T13): rescale only when max grew by > 8 (log2) ----
      if (!__all(mx - m_run <= 8.0f)) {
        const float mn = fmaxf(m_run, mx);
        const float corr = __builtin_amdgcn_exp2f(m_run - mn);
        m_run = mn;
        float cq[4];
#pragma unroll
        for (int r = 0; r < 4; ++r) cq[r] = __shfl(corr, l4 * 4 + r, 64);
#pragma unroll
        for (int db = 0; db < 4; ++db)
#pragma unroll
          for (int r = 0; r < 4; ++r) acc_o[db][r] *= cq[r];
        l_run *= corr;
      }
      float rs = 0.f;
#pragma unroll
      for (int cb = 0; cb < 4; ++cb)
#pragma unroll
        for (int r = 0; r < 4; ++r) {
          const float pv = __builtin_amdgcn_exp2f(accs[cb][r] - m_run);
          accs[cb][r] = pv;
          rs += pv;
        }
      rs += __shfl_xor(rs, 16);
      rs += __shfl_xor(rs, 32);
      l_run += rs;
      // ---- pack P (4 consecutive keys/lane) -> swizzled per-wave LDS ----
#pragma unroll
      for (int cb = 0; cb < 4; ++cb) {
        bf16x4 pk = {(bf16_t)accs[cb][0], (bf16_t)accs[cb][1],
                     (bf16_t)accs[cb][2], (bf16_t)accs[cb][3]};
        const int chunk = (2 * cb + (l4 >> 1)) ^ sw;
        *(bf16x4*)&Ps[w * 1024 + l15 * 64 + chunk * 8 + (l4 & 1) * 4] = pk;
      }
      asm volatile("s_waitcnt lgkmcnt(0)" ::: "memory");
      // ---- read P as A-fragment: P[q=l15][keys l4*8..] ----
      bf16x8 pa[2];
#pragma unroll
      for (int mf = 0; mf < 2; ++mf) {
        const int chunk = (mf * 4 + l4) ^ sw;
        pa[mf] = *(const bf16x8*)&Ps[w * 1024 + l15 * 64 + chunk * 8];
      }
      // ---- O += P V ----
#pragma unroll
      for (int db = 0; db < 4; ++db) {
        const int row = db * 16 + l15;
        const bf16x8 vf0 = *(const bf16x8*)&Vs[buf][row * 64 + ((l4 ^ sw) * 8)];
        const bf16x8 vf1 =
            *(const bf16x8*)&Vs[buf][row * 64 + (((l4 + 4) ^ sw) * 8)];
        acc_o[db] =
            __builtin_amdgcn_mfma_f32_16x16x32_bf16(pa[0], vf0, acc_o[db], 0, 0, 0);
        acc_o[db] =
            __builtin_amdgcn_mfma_f32_16x16x32_bf16(pa[1], vf1, acc_o[db], 0, 0, 0);
      }
    }
    __syncthreads();  // releases buf, drains prefetch
  }

  // ---- epilogue: stage wave tile into Ps (swizzled) -> coalesced u16x8 ----
  float lq[4];
  if (seg < 0) {
#pragma unroll
    for (int r = 0; r < 4; ++r) lq[r] = __shfl(l_run, l4 * 4 + r, 64);
  }
#pragma unroll
  for (int db = 0; db < 4; ++db) {
#pragma unroll
    for (int r = 0; r < 4; ++r) {
      const int row = l4 * 4 + r;
      const int col = db * 16 + l15;
      const float v = seg < 0 ? acc_o[db][r] / lq[r] : acc_o[db][r];
      Ps[w * 1024 + row * 64 + (col ^ ((row & 7) << 3))] = f2bf(v);
    }
  }
  asm volatile("s_waitcnt lgkmcnt(0)" ::: "memory");
  if (seg < 0) {
#pragma unroll
    for (int j = 0; j < 2; ++j) {
      const int cid = j * 64 + lane;
      const int row = cid >> 3, c = cid & 7;
      const u16x8 vch =
          *(const u16x8*)&Ps[w * 1024 + row * 64 + ((c ^ (row & 7)) * 8)];
      *(u16x8*)&O[(size_t)(b * S + qw + row) * D + h * DH + c * 8] = vch;
    }
  } else {
    const size_t base = (size_t)seg * 32768 + (size_t)bh * 1024 + (qw - 1024);
#pragma unroll
    for (int j = 0; j < 2; ++j) {
      const int cid = j * 64 + lane;
      const int row = cid >> 3, c = cid & 7;
      const u16x8 vch =
          *(const u16x8*)&Ps[w * 1024 + row * 64 + ((c ^ (row & 7)) * 8)];
      *(u16x8*)&accP[(base + row) * 64 + c * 8] = vch;
    }
    if (l4 == 0) {
      mP[base + l15] = m_run;
      lP[base + l15] = l_run;
    }
  }
}

// ---------------- combine split-KV partials ----------------
__global__ __launch_bounds__(256) void combine_kernel(
    const u16* __restrict__ accP, const float* __restrict__ mP,
    const float* __restrict__ lP, u16* __restrict__ O) {
  const int id = blockIdx.x * 256 + threadIdx.x;  // 262144 tasks
  const int row = id >> 3;                        // 0..32767
  const int c0 = (id & 7) * 8;
  const float m0 = mP[row], m1 = mP[32768 + row];
  const float l0 = lP[row], l1 = lP[32768 + row];
  const float M = fmaxf(m0, m1);
  const float e0 = __builtin_amdgcn_exp2f(m0 - M);
  const float e1 = __builtin_amdgcn_exp2f(m1 - M);
  const float inv = 1.f / (l0 * e0 + l1 * e1);
  const bf16_t* aP = (const bf16_t*)accP;
  const bf16x8 a0 = *(const bf16x8*)&aP[(size_t)row * 64 + c0];
  const bf16x8 a1 = *(const bf16x8*)&aP[(size_t)(32768 + row) * 64 + c0];
  const int bh = row >> 10, s = 1024 + (row & 1023);
  const int b = bh >> 4, h = bh & 15;
  bf16_t* out = (bf16_t*)O + (size_t)(b * 2048 + s) * 1024 + h * 64 + c0;
  bf16x8 o;
#pragma unroll
  for (int j = 0; j < 8; ++j)
    o[j] = (bf16_t)(((float)a0[j] * e0 + (float)a1[j] * e1) * inv);
  *(bf16x8*)out = o;
}

// ---------------- launch ----------------
extern "C" void kernel_launch(void* const* d_in, const int* in_sizes, int n_in,
                              void* d_out, int out_size, void* d_ws, size_t ws_size,
                              hipStream_t stream) {
  (void)in_sizes; (void)n_in; (void)out_size;
  const float* x   = (const float*)d_in[0];
  const float* wts = (const float*)d_in[1];
  const float* Wq  = (const float*)d_in[2];
  const float* bq  = (const float*)d_in[3];
  const float* Wk  = (const float*)d_in[4];
  const float* bk  = (const float*)d_in[5];
  const float* Wv  = (const float*)d_in[6];
  const float* bv  = (const float*)d_in[7];
  const float* Wo  = (const float*)d_in[8];
  const float* bo  = (const float*)d_in[9];
  float* out = (float*)d_out;

  if (ws_size < 58724352) return;  // need ~56 MB scratch

  char* ws = (char*)d_ws;
  u16* xbf  = (u16*)(ws + 0);          // [4096,1024] bf16 (reused as accP later)
  u16* qbf  = (u16*)(ws + 8388608);
  u16* kbf  = (u16*)(ws + 16777216);
  u16* vbf  = (u16*)(ws + 25165824);
  u16* vt   = (u16*)(ws + 33554432);   // [B,H,DH,S] bf16
  u16* attn = (u16*)(ws + 41943040);   // [4096,1024] bf16
  u16* wqkv = (u16*)(ws + 50331648);   // [3072,1024] bf16 (reused as mP/lP later)
  u16* wob  = (u16*)(ws + 56623104);   // Weff bf16
  float* beff = (float*)(ws + 58720256);

  // overlays (dead after gemm_qkv):
  u16* accP = xbf;                       // 2 x 32768 x 64 bf16 = 8 MB
  float* mP = (float*)(ws + 50331648);   // 2 x 32768 f32
  float* lP = mP + 65536;

  cvt_bf16_kernel<<<2048, 256, 0, stream>>>(x, xbf, 1048576);
  cvt3_bf16_kernel<<<3072, 256, 0, stream>>>(Wq, Wk, Wv, wqkv);
  build_weff_kernel<<<1024, 256, 0, stream>>>(wts, Wo, bo, wob, beff);

  gemm_qkv_kernel<<<dim3(24, 32), 256, 0, stream>>>(xbf, wqkv, bq, bk, bv,
                                                    qbf, kbf, vbf);
  transpose_v_kernel<<<dim3(32, 32), 256, 0, stream>>>(vbf, vt);
  flash_kernel<<<dim3(24, 32), 512, 0, stream>>>(qbf, kbf, vt, attn,
                                                 accP, mP, lP);
  combine_kernel<<<1024, 256, 0, stream>>>(accP, mP, lP, attn);
  gemm_bt_kernel<<<dim3(8, 32), 256, 0, stream>>>(
      attn, wob, beff, out, 4096, 1024, 1024);
}

// Round 5
// 108.194 us; speedup vs baseline: 2.2360x; 1.1706x over previous
//
#include <hip/hip_runtime.h>

// MultiheadAttention: B=2, S=2048, D=1024, H=16, DH=64, NF=4
// Pipeline (5 kernels):
//   1. prep: x->bf16, Wq|Wk|Wv->bf16, Weff=sum w[f]*Wout[f]->bf16, beff
//   2. qkv = x @ Wqkv^T + b  (BK=64 swizzled MFMA GEMM; q pre-scaled log2e/8;
//      v written directly transposed to Vt[b,h,d,s])
//   3. flash attention (8-wave, paired q-tiles, split-KV, swapped QK^T,
//      defer-max with branch-local reduce)
//   4. combine split-KV partials
//   5. out = attn @ Weff^T + beff  (BK=64 swizzled, f32 out)

typedef unsigned short u16;
typedef __bf16 bf16_t;
typedef bf16_t bf16x8 __attribute__((ext_vector_type(8)));
typedef bf16_t bf16x4 __attribute__((ext_vector_type(4)));
typedef float f32x4 __attribute__((ext_vector_type(4)));
typedef u16 u16x8 __attribute__((ext_vector_type(8)));
typedef u16 u16x4 __attribute__((ext_vector_type(4)));

#define DEV __device__ __forceinline__

DEV u16 f2bf(float f) {  // round-to-nearest-even f32 -> bf16
  unsigned u = __float_as_uint(f);
  u += 0x7FFFu + ((u >> 16) & 1u);
  return (u16)(u >> 16);
}

DEV void async_ld16(const void* g, void* lds_wave_uniform) {
  // dst is wave-uniform base; HW writes base + lane*16. Global src is per-lane.
  __builtin_amdgcn_global_load_lds(
      (const __attribute__((address_space(1))) void*)g,
      (__attribute__((address_space(3))) void*)lds_wave_uniform, 16, 0, 0);
}

// ---------------- fused prep: cvt x, cvt W's, build Weff/beff ----------------
__global__ __launch_bounds__(256) void prep_kernel(
    const float* __restrict__ x, const float* __restrict__ Wq,
    const float* __restrict__ Wk, const float* __restrict__ Wv,
    const float* __restrict__ w4, const float* __restrict__ Wout,
    const float* __restrict__ bout, u16* __restrict__ xbf,
    u16* __restrict__ wqkv, u16* __restrict__ Weff, float* __restrict__ beff) {
  constexpr int NX = 1048576;            // x float4s
  constexpr int NW = 262144;             // per-W float4s
  const int stride = gridDim.x * 256;
  for (int id = blockIdx.x * 256 + threadIdx.x; id < NX + 3 * NW + NW;
       id += stride) {
    if (id < NX) {
      const float4 v = ((const float4*)x)[id];
      u16x4 o;
      o[0] = f2bf(v.x); o[1] = f2bf(v.y); o[2] = f2bf(v.z); o[3] = f2bf(v.w);
      ((u16x4*)xbf)[id] = o;
    } else if (id < NX + 3 * NW) {
      const int wi = id - NX;
      const int which = wi >> 18, j = wi & (NW - 1);
      const float* src = which == 0 ? Wq : (which == 1 ? Wk : Wv);
      const float4 v = ((const float4*)src)[j];
      u16x4 o;
      o[0] = f2bf(v.x); o[1] = f2bf(v.y); o[2] = f2bf(v.z); o[3] = f2bf(v.w);
      ((u16x4*)wqkv)[wi] = o;
    } else {
      const int i = id - NX - 3 * NW;
      const float w0 = w4[0], w1 = w4[1], w2 = w4[2], w3 = w4[3];
      const float4* W = (const float4*)Wout;
      const float4 a = W[i], b1 = W[NW + i], b2 = W[2 * NW + i],
                   b3 = W[3 * NW + i];
      u16x4 o;
      o[0] = f2bf(w0 * a.x + w1 * b1.x + w2 * b2.x + w3 * b3.x);
      o[1] = f2bf(w0 * a.y + w1 * b1.y + w2 * b2.y + w3 * b3.y);
      o[2] = f2bf(w0 * a.z + w1 * b1.z + w2 * b2.z + w3 * b3.z);
      o[3] = f2bf(w0 * a.w + w1 * b1.w + w2 * b2.w + w3 * b3.w);
      ((u16x4*)Weff)[i] = o;
      if (i < 256) {
        const float4* B4 = (const float4*)bout;
        const float4 ba = B4[i], c1 = B4[256 + i], c2 = B4[512 + i],
                     c3 = B4[768 + i];
        float4 ob;
        ob.x = w0 * ba.x + w1 * c1.x + w2 * c2.x + w3 * c3.x;
        ob.y = w0 * ba.y + w1 * c1.y + w2 * c2.y + w3 * c3.y;
        ob.z = w0 * ba.z + w1 * c1.z + w2 * c2.z + w3 * c3.z;
        ob.w = w0 * ba.w + w1 * c1.w + w2 * c2.w + w3 * c3.w;
        ((float4*)beff)[i] = ob;
      }
    }
  }
}

// ======== shared GEMM core pieces: 128x128 tile, BK=64, chunk-XOR swizzle ====
// LDS rows are 128B (8 x 16B chunks); chunk c of row r stored at c ^ (r&7).
// Staging: 4 DMAs per matrix per buffer; thread (w,lane) of DMA d covers
// row = d*32 + w*8 + (lane>>3), src chunk = (lane&7) ^ (row&7).

// ---------------- out GEMM: C[M,N](f32) = A @ Bw^T + bias ----------------
__global__ __launch_bounds__(256) void gemm_bt_kernel(
    const u16* __restrict__ A, const u16* __restrict__ Bw,
    const float* __restrict__ bias, float* __restrict__ C, int M, int N, int K) {
  __shared__ u16 LDS[32768];  // As[2][8192] | Bs[2][8192]
  const int tid = threadIdx.x;
  const int w = tid >> 6, lane = tid & 63;
  const int l15 = lane & 15, l4 = lane >> 4;
  const int wr = w >> 1, wc = w & 1;
  const long m0 = (long)blockIdx.y * 128, n0 = (long)blockIdx.x * 128;

  int srow[4], scol[4];
#pragma unroll
  for (int d = 0; d < 4; ++d) {
    srow[d] = d * 32 + w * 8 + (lane >> 3);
    scol[d] = ((lane & 7) ^ (srow[d] & 7)) * 8;
  }
  auto stage = [&](int buf, int kt) {
#pragma unroll
    for (int d = 0; d < 4; ++d) {
      async_ld16(A + (m0 + srow[d]) * K + kt + scol[d],
                 &LDS[buf * 8192 + d * 2048 + w * 512]);
      async_ld16(Bw + (n0 + srow[d]) * K + kt + scol[d],
                 &LDS[16384 + buf * 8192 + d * 2048 + w * 512]);
    }
  };

  f32x4 acc[4][4] = {};
  stage(0, 0);
  __syncthreads();
  const int nt = K / 64;
  for (int t = 0; t < nt; ++t) {
    const int buf = t & 1;
    if (t + 1 < nt) stage(buf ^ 1, (t + 1) * 64);
    bf16x8 af[4][2], bf[4][2];
#pragma unroll
    for (int i = 0; i < 4; ++i) {
      const int ra = wr * 64 + i * 16 + l15;
      const int rb = wc * 64 + i * 16 + l15;
#pragma unroll
      for (int ks = 0; ks < 2; ++ks) {
        af[i][ks] = *(const bf16x8*)&LDS[buf * 8192 + ra * 64 +
                                         (((ks * 4 + l4) ^ (ra & 7)) * 8)];
        bf[i][ks] = *(const bf16x8*)&LDS[16384 + buf * 8192 + rb * 64 +
                                         (((ks * 4 + l4) ^ (rb & 7)) * 8)];
      }
    }
#pragma unroll
    for (int i = 0; i < 4; ++i)
#pragma unroll
      for (int j = 0; j < 4; ++j) {
        acc[i][j] = __builtin_amdgcn_mfma_f32_16x16x32_bf16(af[i][0], bf[j][0],
                                                            acc[i][j], 0, 0, 0);
        acc[i][j] = __builtin_amdgcn_mfma_f32_16x16x32_bf16(af[i][1], bf[j][1],
                                                            acc[i][j], 0, 0, 0);
      }
    __syncthreads();
  }

#pragma unroll
  for (int i = 0; i < 4; ++i) {
    const long row0 = m0 + wr * 64 + i * 16 + l4 * 4;
#pragma unroll
    for (int j = 0; j < 4; ++j) {
      const long col = n0 + wc * 64 + j * 16 + l15;
      const float bb = bias[col];
#pragma unroll
      for (int r = 0; r < 4; ++r)
        C[(row0 + r) * N + col] = acc[i][j][r] + bb;
    }
  }
}

// ---------------- fused QKV GEMM: [4096,1024] x [3072,1024]^T ----------------
// Q pre-scaled by log2e/8. q/k: LDS-coalesced bf16 stores. v: written
// TRANSPOSED to Vt[b,h,d,s] (via transposed swizzled LDS tile).
__global__ __launch_bounds__(256) void gemm_qkv_kernel(
    const u16* __restrict__ A, const u16* __restrict__ Bw,
    const float* __restrict__ bq, const float* __restrict__ bk,
    const float* __restrict__ bv, u16* __restrict__ qo, u16* __restrict__ ko,
    u16* __restrict__ vt) {
  constexpr int K = 1024;
  __shared__ u16 LDS[32768];  // As[2][8192] | Bs[2][8192]; epilogue C-tile
  const int tid = threadIdx.x;
  const int w = tid >> 6, lane = tid & 63;
  const int l15 = lane & 15, l4 = lane >> 4;
  const int wr = w >> 1, wc = w & 1;
  const long m0 = (long)blockIdx.y * 128, n0 = (long)blockIdx.x * 128;
  const int seg = blockIdx.x >> 3;  // 0=q 1=k 2=v
  const float* bias = seg == 0 ? bq : (seg == 1 ? bk : bv);
  const float scale = seg == 0 ? 0.18033688011112042f : 1.0f;  // log2e/8

  int srow[4], scol[4];
#pragma unroll
  for (int d = 0; d < 4; ++d) {
    srow[d] = d * 32 + w * 8 + (lane >> 3);
    scol[d] = ((lane & 7) ^ (srow[d] & 7)) * 8;
  }
  auto stage = [&](int buf, int kt) {
#pragma unroll
    for (int d = 0; d < 4; ++d) {
      async_ld16(A + (m0 + srow[d]) * K + kt + scol[d],
                 &LDS[buf * 8192 + d * 2048 + w * 512]);
      async_ld16(Bw + (n0 + srow[d]) * K + kt + scol[d],
                 &LDS[16384 + buf * 8192 + d * 2048 + w * 512]);
    }
  };

  f32x4 acc[4][4] = {};
  stage(0, 0);
  __syncthreads();
  const int nt = K / 64;
  for (int t = 0; t < nt; ++t) {
    const int buf = t & 1;
    if (t + 1 < nt) stage(buf ^ 1, (t + 1) * 64);
    bf16x8 af[4][2], bf[4][2];
#pragma unroll
    for (int i = 0; i < 4; ++i) {
      const int ra = wr * 64 + i * 16 + l15;
      const int rb = wc * 64 + i * 16 + l15;
#pragma unroll
      for (int ks = 0; ks < 2; ++ks) {
        af[i][ks] = *(const bf16x8*)&LDS[buf * 8192 + ra * 64 +
                                         (((ks * 4 + l4) ^ (ra & 7)) * 8)];
        bf[i][ks] = *(const bf16x8*)&LDS[16384 + buf * 8192 + rb * 64 +
                                         (((ks * 4 + l4) ^ (rb & 7)) * 8)];
      }
    }
#pragma unroll
    for (int i = 0; i < 4; ++i)
#pragma unroll
      for (int j = 0; j < 4; ++j) {
        acc[i][j] = __builtin_amdgcn_mfma_f32_16x16x32_bf16(af[i][0], bf[j][0],
                                                            acc[i][j], 0, 0, 0);
        acc[i][j] = __builtin_amdgcn_mfma_f32_16x16x32_bf16(af[i][1], bf[j][1],
                                                            acc[i][j], 0, 0, 0);
      }
    __syncthreads();
  }

  const long ccol0 = n0 - (long)seg * 1024;
  if (seg < 2) {
    // ---- q/k epilogue: row-major swizzled tile -> coalesced u16x8 ----
    u16* outp = seg == 0 ? qo : ko;
#pragma unroll
    for (int i = 0; i < 4; ++i) {
#pragma unroll
      for (int j = 0; j < 4; ++j) {
        const int colb = wc * 64 + j * 16 + l15;
        const float bb = bias[ccol0 + colb];
#pragma unroll
        for (int r = 0; r < 4; ++r) {
          const int row = wr * 64 + i * 16 + l4 * 4 + r;
          LDS[row * 128 + (colb ^ ((row & 15) << 3))] =
              f2bf((acc[i][j][r] + bb) * scale);
        }
      }
    }
    __syncthreads();
#pragma unroll
    for (int p = 0; p < 8; ++p) {
      const int cid = p * 256 + tid;
      const int row = cid >> 4, c = cid & 15;
      const u16x8 vch = *(const u16x8*)&LDS[row * 128 + ((c ^ (row & 15)) * 8)];
      *(u16x8*)&outp[(m0 + row) * 1024 + ccol0 + c * 8] = vch;
    }
  } else {
    // ---- v epilogue: transposed tile SMt[col][row], write Vt[b,h,d,s] ----
    const int b = (int)(m0 >> 11);
    const int s0 = (int)(m0 & 2047);
#pragma unroll
    for (int i = 0; i < 4; ++i) {
#pragma unroll
      for (int j = 0; j < 4; ++j) {
        const int colb = wc * 64 + j * 16 + l15;
        const float bb = bias[ccol0 + colb];
#pragma unroll
        for (int r = 0; r < 4; ++r) {
          const int row = wr * 64 + i * 16 + l4 * 4 + r;
          LDS[colb * 128 + (row ^ ((colb & 15) << 3))] = f2bf(acc[i][j][r] + bb);
        }
      }
    }
    __syncthreads();
#pragma unroll
    for (int p = 0; p < 8; ++p) {
      const int cid = p * 256 + tid;
      const int c = cid >> 4, r0 = (cid & 15) * 8;
      const u16x8 vch = *(const u16x8*)&LDS[c * 128 + (r0 ^ ((c & 15) << 3))];
      const int gcol = (int)ccol0 + c;  // 0..1023 within v
      const int h = gcol >> 6, d = gcol & 63;
      *(u16x8*)&vt[(size_t)((b * 16 + h) * 64 + d) * 2048 + s0 + r0] = vch;
    }
  }
}

// ---------------- causal flash attention v5 ----------------
// 512 threads = 8 waves covering q-tiles (2i, 2i+1): one shared KV stream.
// x' < 8: full kv range, final output. x' >= 8: split-KV halves -> partials.
// Heavy-first remap. Swapped QK^T; defer-max with reduce-in-branch;
// per-lane partial l reduced once at epilogue.
__global__ __launch_bounds__(512, 6) void flash_kernel(
    const u16* __restrict__ Q, const u16* __restrict__ Kg,
    const u16* __restrict__ Vt, u16* __restrict__ O,
    u16* __restrict__ accP, float* __restrict__ mP, float* __restrict__ lP) {
  constexpr int S = 2048, D = 1024, DH = 64;
  __shared__ u16 Ks[2][4096];  // [key][feat], XOR-swizzled 16B chunks
  __shared__ u16 Vs[2][4096];  // [d][key], XOR-swizzled 16B chunks
  __shared__ u16 Ps[8192];     // 8 waves x [16 q][64 key], XOR-swizzled
  const int tid = threadIdx.x;
  const int w = tid >> 6, lane = tid & 63;
  const int l15 = lane & 15, l4 = lane >> 4;
  const int bh = blockIdx.y, b = bh >> 4, h = bh & 15;
  const int x = 23 - (int)blockIdx.x;  // heavy blocks dispatched first
  int bi, kvlo, kvhi, seg;
  if (x < 8) {
    bi = x; seg = -1; kvlo = 0; kvhi = 2 * bi + 2;
  } else {
    const int idx = x - 8;
    bi = 8 + (idx >> 1); seg = idx & 1;
    kvlo = seg ? (bi + 1) : 0;
    kvhi = seg ? (2 * bi + 2) : (bi + 1);
  }
  const int qw = 128 * bi + w * 16;  // wave's first q row within bh
  const int qtile = qw >> 6;

  const u16* Kbh = Kg + (size_t)b * S * D + h * DH;
  const u16* Vbh = Vt + (size_t)bh * DH * S;

  const int srow = tid >> 3;
  const int scol = ((tid & 7) ^ (srow & 7)) * 8;
  const int sw = l15 & 7;

  bf16x8 qf[2];
  {
    const u16* qp = Q + (size_t)(b * S + qw + l15) * D + h * DH + l4 * 8;
    qf[0] = *(const bf16x8*)qp;
    qf[1] = *(const bf16x8*)(qp + 32);
  }

  f32x4 acc_o[4] = {};
  float m_run = -3e38f, l_run = 0.f;  // l_run: per-lane PARTIAL (16 keys/step)

  async_ld16(Kbh + (size_t)(kvlo * 64 + srow) * D + scol, &Ks[0][w * 512]);
  async_ld16(Vbh + (size_t)srow * S + kvlo * 64 + scol, &Vs[0][w * 512]);
  __syncthreads();

  for (int it = kvlo; it < kvhi; ++it) {
    const int buf = (it - kvlo) & 1;
    if (it + 1 < kvhi) {
      async_ld16(Kbh + (size_t)((it + 1) * 64 + srow) * D + scol,
                 &Ks[buf ^ 1][w * 512]);
      async_ld16(Vbh + (size_t)srow * S + (it + 1) * 64 + scol,
                 &Vs[buf ^ 1][w * 512]);
    }
    if (it <= qtile) {
      // ---- S^T = K Q^T ----
      f32x4 accs[4] = {};
#pragma unroll
      for (int cb = 0; cb < 4; ++cb) {
        const int row = cb * 16 + l15;
        const bf16x8 kf0 = *(const bf16x8*)&Ks[buf][row * 64 + ((l4 ^ sw) * 8)];
        const bf16x8 kf1 =
            *(const bf16x8*)&Ks[buf][row * 64 + (((l4 + 4) ^ sw) * 8)];
        accs[cb] =
            __builtin_amdgcn_mfma_f32_16x16x32_bf16(kf0, qf[0], accs[cb], 0, 0, 0);
        accs[cb] =
            __builtin_amdgcn_mfma_f32_16x16x32_bf16(kf1, qf[1], accs[cb], 0, 0, 0);
      }
      // ---- mask (diag) + local max over this lane's 16 keys ----
      float mx = -3e38f;
      if (it == qtile) {
#pragma unroll
        for (int cb = 0; cb < 4; ++cb)
#pragma unroll
          for (int r = 0; r < 4; ++r) {
            float s_ = accs[cb][r];
            if (it * 64 + cb * 16 + l4 * 4 + r > qw + l15) s_ = -3e38f;
            accs[cb][r] = s_;
            mx = fmaxf(mx, s_);
          }
      } else {
#pragma unroll
        for (int cb = 0; cb < 4; ++cb)
#pragma unroll
          for (int r = 0; r < 4; ++r) mx = fmaxf(mx, accs[cb][r]);
      }
      // ---- defer-max: rescale (and row-reduce) only when max grew > 8 ----
      if (!__all(mx - m_run <= 8.0f)) {
        mx = fmaxf(mx, __shfl_xor(mx, 16));
        mx = fmaxf(mx, __shfl_xor(mx, 32));
        const float mn = fmaxf(m_run, mx);
        const float corr = __builtin_amdgcn_exp2f(m_run - mn);
        m_run = mn;
        float cq[4];
#pragma unroll
        for (int r = 0; r < 4; ++r) cq[r] = __shfl(corr, l4 * 4 + r, 64);
#pragma unroll
        for (int db = 0; db < 4; ++db)
#pragma unroll
          for (int r = 0; r < 4; ++r) acc_o[db][r] *= cq[r];
        l_run *= corr;
      }
      float rs = 0.f;
#pragma unroll
      for (int cb = 0; cb < 4; ++cb)
#pragma unroll
        for (int r = 0; r < 4; ++r) {
          const float pv = __builtin_amdgcn_exp2f(accs[cb][r] - m_run);
          accs[cb][r] = pv;
          rs += pv;
        }
      l_run += rs;  // per-lane partial; reduced at epilogue
      // ---- pack P -> swizzled per-wave LDS ----
#pragma unroll
      for (int cb = 0; cb < 4; ++cb) {
        bf16x4 pk = {(bf16_t)accs[cb][0], (bf16_t)accs[cb][1],
                     (bf16_t)accs[cb][2], (bf16_t)accs[cb][3]};
        const int chunk = (2 * cb + (l4 >> 1)) ^ sw;
        *(bf16x4*)&Ps[w * 1024 + l15 * 64 + chunk * 8 + (l4 & 1) * 4] = pk;
      }
      asm volatile("s_waitcnt lgkmcnt(0)" ::: "memory");
      bf16x8 pa[2];
#pragma unroll
      for (int mf = 0; mf < 2; ++mf) {
        const int chunk = (mf * 4 + l4) ^ sw;
        pa[mf] = *(const bf16x8*)&Ps[w * 1024 + l15 * 64 + chunk * 8];
      }
      // ---- O += P V ----
#pragma unroll
      for (int db = 0; db < 4; ++db) {
        const int row = db * 16 + l15;
        const bf16x8 vf0 = *(const bf16x8*)&Vs[buf][row * 64 + ((l4 ^ sw) * 8)];
        const bf16x8 vf1 =
            *(const bf16x8*)&Vs[buf][row * 64 + (((l4 + 4) ^ sw) * 8)];
        acc_o[db] =
            __builtin_amdgcn_mfma_f32_16x16x32_bf16(pa[0], vf0, acc_o[db], 0, 0, 0);
        acc_o[db] =
            __builtin_amdgcn_mfma_f32_16x16x32_bf16(pa[1], vf1, acc_o[db], 0, 0, 0);
      }
    }
    __syncthreads();
  }

  // ---- epilogue: reduce l, stage into Ps (swizzled) -> coalesced u16x8 ----
  float l_tot = l_run;
  l_tot += __shfl_xor(l_tot, 16);
  l_tot += __shfl_xor(l_tot, 32);
  float lq[4];
  if (seg < 0) {
#pragma unroll
    for (int r = 0; r < 4; ++r) lq[r] = __shfl(l_tot, l4 * 4 + r, 64);
  }
#pragma unroll
  for (int db = 0; db < 4; ++db) {
#pragma unroll
    for (int r = 0; r < 4; ++r) {
      const int row = l4 * 4 + r;
      const int col = db * 16 + l15;
      const float v = seg < 0 ? acc_o[db][r] / lq[r] : acc_o[db][r];
      Ps[w * 1024 + row * 64 + (col ^ ((row & 7) << 3))] = f2bf(v);
    }
  }
  asm volatile("s_waitcnt lgkmcnt(0)" ::: "memory");
  if (seg < 0) {
#pragma unroll
    for (int j = 0; j < 2; ++j) {
      const int cid = j * 64 + lane;
      const int row = cid >> 3, c = cid & 7;
      const u16x8 vch =
          *(const u16x8*)&Ps[w * 1024 + row * 64 + ((c ^ (row & 7)) * 8)];
      *(u16x8*)&O[(size_t)(b * S + qw + row) * D + h * DH + c * 8] = vch;
    }
  } else {
    const size_t base = (size_t)seg * 32768 + (size_t)bh * 1024 + (qw - 1024);
#pragma unroll
    for (int j = 0; j < 2; ++j) {
      const int cid = j * 64 + lane;
      const int row = cid >> 3, c = cid & 7;
      const u16x8 vch =
          *(const u16x8*)&Ps[w * 1024 + row * 64 + ((c ^ (row & 7)) * 8)];
      *(u16x8*)&accP[(base + row) * 64 + c * 8] = vch;
    }
    if (l4 == 0) {
      mP[base + l15] = m_run;
      lP[base + l15] = l_tot;
    }
  }
}

// ---------------- combine split-KV partials ----------------
__global__ __launch_bounds__(256) void combine_kernel(
    const u16* __restrict__ accP, const float* __restrict__ mP,
    const float* __restrict__ lP, u16* __restrict__ O) {
  const int id = blockIdx.x * 256 + threadIdx.x;  // 262144 tasks
  const int row = id >> 3;                        // 0..32767
  const int c0 = (id & 7) * 8;
  const float m0 = mP[row], m1 = mP[32768 + row];
  const float l0 = lP[row], l1 = lP[32768 + row];
  const float M = fmaxf(m0, m1);
  const float e0 = __builtin_amdgcn_exp2f(m0 - M);
  const float e1 = __builtin_amdgcn_exp2f(m1 - M);
  const float inv = 1.f / (l0 * e0 + l1 * e1);
  const bf16_t* aP = (const bf16_t*)accP;
  const bf16x8 a0 = *(const bf16x8*)&aP[(size_t)row * 64 + c0];
  const bf16x8 a1 = *(const bf16x8*)&aP[(size_t)(32768 + row) * 64 + c0];
  const int bh = row >> 10, s = 1024 + (row & 1023);
  const int b = bh >> 4, h = bh & 15;
  bf16_t* out = (bf16_t*)O + (size_t)(b * 2048 + s) * 1024 + h * 64 + c0;
  bf16x8 o;
#pragma unroll
  for (int j = 0; j < 8; ++j)
    o[j] = (bf16_t)(((float)a0[j] * e0 + (float)a1[j] * e1) * inv);
  *(bf16x8*)out = o;
}

// ---------------- launch ----------------
extern "C" void kernel_launch(void* const* d_in, const int* in_sizes, int n_in,
                              void* d_out, int out_size, void* d_ws, size_t ws_size,
                              hipStream_t stream) {
  (void)in_sizes; (void)n_in; (void)out_size;
  const float* x   = (const float*)d_in[0];
  const float* wts = (const float*)d_in[1];
  const float* Wq  = (const float*)d_in[2];
  const float* bq  = (const float*)d_in[3];
  const float* Wk  = (const float*)d_in[4];
  const float* bk  = (const float*)d_in[5];
  const float* Wv  = (const float*)d_in[6];
  const float* bv  = (const float*)d_in[7];
  const float* Wo  = (const float*)d_in[8];
  const float* bo  = (const float*)d_in[9];
  float* out = (float*)d_out;

  if (ws_size < 58724352) return;  // need ~56 MB scratch

  char* ws = (char*)d_ws;
  u16* xbf  = (u16*)(ws + 0);          // [4096,1024] bf16 (reused as accP later)
  u16* qbf  = (u16*)(ws + 8388608);
  u16* kbf  = (u16*)(ws + 16777216);
  u16* vt   = (u16*)(ws + 33554432);   // [B,H,DH,S] bf16
  u16* attn = (u16*)(ws + 41943040);   // [4096,1024] bf16
  u16* wqkv = (u16*)(ws + 50331648);   // [3072,1024] bf16 (reused as mP/lP)
  u16* wob  = (u16*)(ws + 56623104);   // Weff bf16
  float* beff = (float*)(ws + 58720256);

  // overlays (dead after gemm_qkv):
  u16* accP = xbf;                       // 2 x 32768 x 64 bf16 = 8 MB
  float* mP = (float*)(ws + 50331648);   // 2 x 32768 f32
  float* lP = mP + 65536;

  prep_kernel<<<2048, 256, 0, stream>>>(x, Wq, Wk, Wv, wts, Wo, bo,
                                        xbf, wqkv, wob, beff);
  gemm_qkv_kernel<<<dim3(24, 32), 256, 0, stream>>>(xbf, wqkv, bq, bk, bv,
                                                    qbf, kbf, vt);
  flash_kernel<<<dim3(24, 32), 512, 0, stream>>>(qbf, kbf, vt, attn,
                                                 accP, mP, lP);
  combine_kernel<<<1024, 256, 0, stream>>>(accP, mP, lP, attn);
  gemm_bt_kernel<<<dim3(8, 32), 256, 0, stream>>>(
      attn, wob, beff, out, 4096, 1024, 1024);
}